// Round 11
// baseline (547.013 us; speedup 1.0000x reference)
//
#include <hip/hip_runtime.h>
#include <stdint.h>

#define EPS 1e-5f

typedef __attribute__((ext_vector_type(8))) short short8;
typedef __attribute__((ext_vector_type(4))) float floatx4;
typedef __attribute__((ext_vector_type(4))) unsigned uintx4;
typedef unsigned short u16;

__device__ __forceinline__ u16 f2bf(float f) {
  unsigned u = __builtin_bit_cast(unsigned, f);
  u += 0x7fffu + ((u >> 16) & 1u);
  return (u16)(u >> 16);
}
__device__ __forceinline__ float bf2f(u16 h) {
  return __builtin_bit_cast(float, (unsigned)h << 16);
}
__device__ __forceinline__ unsigned pack2bf(float a, float b) {
  return (unsigned)f2bf(a) | ((unsigned)f2bf(b) << 16);
}
__device__ __forceinline__ float silu_f(float x) { return x / (1.f + __expf(-x)); }
__device__ __forceinline__ float wave_sum(float x) {
  for (int off = 32; off > 0; off >>= 1) x += __shfl_xor(x, off);
  return x;
}

// LDS-only barrier: drains ds ops (lgkmcnt) but NOT global loads (vmcnt).
// All cross-wave deps in attn_kernel are through LDS; global loads are
// register-consumed (compiler inserts vmcnt waits at use). This removes the
// structural s_waitcnt vmcnt(0) __syncthreads would emit before s_barrier.
#define BARRIER()                                         \
  do {                                                    \
    asm volatile("s_waitcnt lgkmcnt(0)" ::: "memory");    \
    __builtin_amdgcn_s_barrier();                         \
  } while (0)

// ---------------------------------------------------------------------------
// prep: swizzle weights into MFMA fragment order.
// w1f layout (conv-fold): [tap 0..3][nt 0..3][ks 0..3][lane][8]; tap 0..2 =
// conv taps, tap 3 = hp. woT packed [k4][64][4] for coalesced dwordx4.
// ---------------------------------------------------------------------------
__global__ void prep_kernel(const float* __restrict__ hp_w, const float* __restrict__ conv_w,
                            const float* __restrict__ attn_in_w,
                            const float* __restrict__ attn_out_w,
                            const float* __restrict__ tw_w, const float* __restrict__ r1_w,
                            const float* __restrict__ r2_w,
                            u16* __restrict__ w1f, u16* __restrict__ w2f,
                            float* __restrict__ woT,
                            float* __restrict__ twT, float* __restrict__ r1T,
                            float* __restrict__ r2T) {
  int t = blockIdx.x * 256 + threadIdx.x;  // 0..65535
  if (t < 32768) {
    int j = t & 7, lane = (t >> 3) & 63, ks = (t >> 9) & 3, nt = (t >> 11) & 3, tp = t >> 13;
    int k = ks * 32 + ((lane >> 4) << 3) + j;
    int c = nt * 16 + (lane & 15);
    float v = (tp == 3) ? hp_w[c * 128 + k] : conv_w[c * 384 + k * 3 + tp];
    w1f[t] = f2bf(v);
  }
  if (t < 8192) {
    int j = t & 7, lane = (t >> 3) & 63, ks = (t >> 9) & 1, nt = t >> 10;
    int k = ks * 32 + ((lane >> 4) << 3) + j;
    int n = nt * 16 + (lane & 15);
    w2f[t] = f2bf(attn_in_w[(64 + n) * 64 + k]);
  }
  if (t < 1024) {  // woT[(k4*64+j)*4+i] = attn_out_w[j][k4*4+i]
    int j = t & 63, k4 = t >> 6;
#pragma unroll
    for (int i = 0; i < 4; ++i)
      woT[(k4 * 64 + j) * 4 + i] = attn_out_w[j * 64 + k4 * 4 + i];
  }
  if (t < 8320) {  // twT[k4 0..64][mid 0..127][4]; k=257..259 zero-padded
    int mid = t & 127, k4 = t >> 7;
#pragma unroll
    for (int i = 0; i < 4; ++i) {
      int k = k4 * 4 + i;
      twT[t * 4 + i] = (k < 257) ? tw_w[mid * 257 + k] : 0.f;
    }
  }
  if (t < 16384) {  // r1T/r2T[k4 0..63][o 0..255][4]
    int o = t & 255, k4 = t >> 8;
#pragma unroll
    for (int i = 0; i < 4; ++i) {
      r1T[t * 4 + i] = r1_w[o * 256 + k4 * 4 + i];
      r2T[t * 4 + i] = r2_w[o * 256 + k4 * 4 + i];
    }
  }
}

// ---------------------------------------------------------------------------
// team_kernel: per-team q = temb[t]@qp_w.T + qp_b ; qh = q@wq.T + bq
// ---------------------------------------------------------------------------
__global__ __launch_bounds__(64) void team_kernel(
    const float* __restrict__ temb, const float* __restrict__ qp_w,
    const float* __restrict__ qp_b, const float* __restrict__ attn_in_w,
    const float* __restrict__ attn_in_b,
    float* __restrict__ Qg, float* __restrict__ QHg) {
  __shared__ float e[96];
  __shared__ float qv[64];
  const int t = blockIdx.x;   // team id 0..399
  const int o = threadIdx.x;  // 0..63
  for (int i = o; i < 96; i += 64) e[i] = temb[t * 96 + i];
  __syncthreads();
  float acc = qp_b[o];
  for (int k = 0; k < 96; ++k) acc += e[k] * qp_w[o * 96 + k];
  qv[o] = acc;
  Qg[t * 64 + o] = acc;
  __syncthreads();
  float acc2 = attn_in_b[o];
  for (int k = 0; k < 64; ++k) acc2 += qv[k] * attn_in_w[o * 64 + k];
  QHg[t * 64 + o] = acc2;
}

// ---------------------------------------------------------------------------
// attn_kernel (r19): 2 TILES PER PHASE-CYCLE + vmcnt-FREE BARRIERS.
// Amortizes the fixed per-phase cost (the r4/r8-validated lever) over 2x
// work: 4 iterations x {stage both tiles | G1 both | G2 both | wave-local
// tail} = 3 barriers per 2 units (was 4 per unit). Tail: wave w owns output
// (tile=w>>1, query=w&1) — own q/qh regs, scores->a_s->PV->op->outproj all
// in-wave (LDS write->read within a wave needs only lgkmcnt) => NO tail
// barrier. BARRIER() = lgkmcnt(0)+s_barrier: all cross-wave deps are LDS;
// global prefetch loads stay in flight until their register use (kills the
// structural vmcnt(0) drain identified in r9).
// s = blockIdx&1 is block-constant (pairs advance by 2048) => uniform ptrs.
// Phantom-row discipline identical to r14 (discarded M-rows).
// LDS 78976 B -> 2 blocks/CU. Diagnostics: attn ~165-195us; VGPR ~190-230
// (FETCH jump => spill); absmax <= 0.0196.
// ---------------------------------------------------------------------------
__global__ __launch_bounds__(256, 2) void attn_kernel(
    const int* __restrict__ idA, const int* __restrict__ idB,
    const float* __restrict__ hnA, const float* __restrict__ hnB,
    const int* __restrict__ oppA, const int* __restrict__ oppB,
    const float* __restrict__ mskA, const float* __restrict__ mskB,
    const float* __restrict__ temb, const float* __restrict__ conv_b,
    const float* __restrict__ cbn_g, const float* __restrict__ cbn_b,
    const float* __restrict__ cbn_rm, const float* __restrict__ cbn_rv,
    const float* __restrict__ hp_b,
    const float* __restrict__ attn_in_b, const float* __restrict__ attn_out_b,
    const float* __restrict__ ln_g, const float* __restrict__ ln_b,
    const u16* __restrict__ w1f, const u16* __restrict__ w2f,
    const float* __restrict__ woT,
    const float* __restrict__ Qg, const float* __restrict__ QHg,
    float* __restrict__ ATT) {
  // arena byte map (77952 B):
  //   [    0, 11424) xs0 : u16 [42][136]
  //   [11424, 22848) xs1 : u16 [42][136]
  //   [22848, 29760) kvb0: u16 [48][72]   (tail aliases a_s/op here)
  //   [29760, 36672) kvb1: u16 [48][72]
  //   [36672, 77952) KVP : f32 [2][40][129]
  __shared__ __align__(16) u16 arena[38976];
  __shared__ __align__(16) float qh_s[4 * 64];
  u16* xs0 = arena;
  u16* xs1 = arena + 5712;
  u16* kvb0 = arena + 11424;
  u16* kvb1 = arena + 14880;
  float* KVP = (float*)(arena + 18336);
  float* a_s = (float*)(arena + 11424);  // [4 waves][4][40]  (kvb0 alias)
  float* op = a_s + 640;                 // [4 waves][64]

  const int tid = threadIdx.x;
  const int lane = tid & 63;
  const int wv = tid >> 6;
  const int qd = lane >> 4;
  const int l16 = lane & 15;
  const int tw = wv >> 1;  // tail: which tile this wave serves
  const int qi = wv & 1;   // tail: which query (A/B)

  const int s = blockIdx.x & 1;        // block-constant hist side
  const int bbase = blockIdx.x >> 1;   // tile b = bbase + (2*it+t)*1024
  const float* phn = s ? hnB : hnA;
  const int* popp = s ? oppB : oppA;
  const float* pmsk = s ? mskB : mskA;
  const int* pid = qi ? idB : idA;     // per-wave query id array

  const int c_lane = wv * 16 + l16;
  const float sc_c = rsqrtf(cbn_rv[c_lane] + EPS) * cbn_g[c_lane];
  const float sh_c = cbn_b[c_lane] - cbn_rm[c_lane] * sc_c;
  const float hpb_c = hp_b[c_lane];
  const float cvb_c = conv_b[c_lane];
  const float lng = ln_g[lane], lnb = ln_b[lane];
  const float aob = attn_out_b[lane];
  const float kb0 = attn_in_b[64 + (wv * 2 + 0) * 16 + l16];
  const float kb1 = attn_in_b[64 + (wv * 2 + 1) * 16 + l16];

  // one-time conv-pad rows for both tiles
  if (tid < 136) {
    xs0[tid] = 0;
    xs0[41 * 136 + tid] = 0;
    xs1[tid] = 0;
    xs1[41 * 136 + tid] = 0;
  }

  short8 w1r[4][4];  // [tap: 0..2 conv, 3 hp][ks]
#pragma unroll
  for (int tp = 0; tp < 4; ++tp)
#pragma unroll
    for (int ks = 0; ks < 4; ++ks)
      w1r[tp][ks] = *reinterpret_cast<const short8*>(
          w1f + (((tp * 4 + wv) * 4 + ks) * 64 + lane) * 8);
  short8 w2r[2][2];
#pragma unroll
  for (int ntl = 0; ntl < 2; ++ntl)
#pragma unroll
    for (int ks = 0; ks < 2; ++ks)
      w2r[ntl][ks] = *reinterpret_cast<const short8*>(
          w2f + (((wv * 2 + ntl) * 2 + ks) * 64 + lane) * 8);

  // ---- iteration-0 x data for both tiles ----
  unsigned xr[2][12];
  float mkr[2][3];
#pragma unroll
  for (int t = 0; t < 2; ++t) {
    int pb = bbase + t * 1024;
#pragma unroll
    for (int j = 0; j < 3; ++j) {
      int sidx = j * 256 + tid;
      int srow = sidx >> 4, scg = sidx & 15;
      if (srow < 40) {
        int mrow = pb * 40 + srow;
        mkr[t][j] = pmsk[mrow];
        const float* p = (scg < 4)
                             ? phn + (size_t)mrow * 32 + scg * 8
                             : temb + (size_t)popp[mrow] * 96 + (scg * 8 - 32);
        floatx4 f0 = *reinterpret_cast<const floatx4*>(p);
        floatx4 f1 = *reinterpret_cast<const floatx4*>(p + 4);
        xr[t][j * 4 + 0] = pack2bf(f0[0], f0[1]);
        xr[t][j * 4 + 1] = pack2bf(f0[2], f0[3]);
        xr[t][j * 4 + 2] = pack2bf(f1[0], f1[1]);
        xr[t][j * 4 + 3] = pack2bf(f1[2], f1[3]);
      } else {
        mkr[t][j] = 0.f;
        xr[t][j * 4 + 0] = xr[t][j * 4 + 1] = xr[t][j * 4 + 2] = xr[t][j * 4 + 3] = 0u;
      }
    }
  }

  // per-wave q/qh/mask for its (tile tw, query qi), iteration 0
  float qreg, qhreg, m_l = 0.f;
  {
    int b0 = bbase + tw * 1024;
    int id0 = pid[b0];
    qreg = Qg[id0 * 64 + lane];
    qhreg = QHg[id0 * 64 + lane];
    if (lane < 40) m_l = pmsk[b0 * 40 + lane];
  }
  BARRIER();  // pad-zero visible

#pragma unroll 1
  for (int it = 0; it < 4; ++it) {
    int bt0 = bbase + (2 * it) * 1024;
    int bt1 = bt0 + 1024;
    int b_w = bbase + (2 * it + tw) * 1024;  // this wave's tile b

    // ---- stage both tiles ----
#pragma unroll
    for (int t = 0; t < 2; ++t) {
      u16* xsd = t ? xs1 : xs0;
#pragma unroll
      for (int j = 0; j < 3; ++j) {
        int sidx = j * 256 + tid;
        int srow = sidx >> 4;
        if (srow < 40) {
          bool keep = mkr[t][j] != 0.f;
          uintx4 v;
          v[0] = keep ? xr[t][j * 4 + 0] : 0u;
          v[1] = keep ? xr[t][j * 4 + 1] : 0u;
          v[2] = keep ? xr[t][j * 4 + 2] : 0u;
          v[3] = keep ? xr[t][j * 4 + 3] : 0u;
          *reinterpret_cast<uintx4*>(xsd + (srow + 1) * 136 + (sidx & 15) * 8) = v;
        }
      }
    }
    BARRIER();  // b1: xs ready

    // ---- prefetch next iteration (loads stay in flight: no vmcnt drain) ----
    float pf[2][3][8];
    float mknew[2][3];
    float qn, qhn, m_n = 0.f;
    {
      int adv = (it < 3) ? 2048 : 0;
#pragma unroll
      for (int t = 0; t < 2; ++t) {
        int pb = (t ? bt1 : bt0) + adv;
#pragma unroll
        for (int j = 0; j < 3; ++j) {
          int sidx = j * 256 + tid;
          int srow = sidx >> 4, scg = sidx & 15;
          if (srow < 40) {
            int mrow = pb * 40 + srow;
            mknew[t][j] = pmsk[mrow];
            const float* p = (scg < 4)
                                 ? phn + (size_t)mrow * 32 + scg * 8
                                 : temb + (size_t)popp[mrow] * 96 + (scg * 8 - 32);
            *reinterpret_cast<floatx4*>(&pf[t][j][0]) = *reinterpret_cast<const floatx4*>(p);
            *reinterpret_cast<floatx4*>(&pf[t][j][4]) = *reinterpret_cast<const floatx4*>(p + 4);
          } else {
            mknew[t][j] = 0.f;
#pragma unroll
            for (int q = 0; q < 8; ++q) pf[t][j][q] = 0.f;
          }
        }
      }
      int bn = b_w + adv;
      int idn = pid[bn];
      qn = Qg[idn * 64 + lane];
      qhn = QHg[idn * 64 + lane];
      if (lane < 40) m_n = pmsk[bn * 40 + lane];
    }

    // ---- GEMM1' conv-fold, both tiles ----
#pragma unroll 1
    for (int t = 0; t < 2; ++t) {
      const u16* xsrc = t ? xs1 : xs0;
      u16* kdst = t ? kvb1 : kvb0;
#pragma unroll 1
      for (int mt = 0; mt < 3; ++mt) {
        floatx4 ach = {0.f, 0.f, 0.f, 0.f};
        floatx4 acv = {0.f, 0.f, 0.f, 0.f};
#pragma unroll
        for (int ks = 0; ks < 4; ++ks) {
          const u16* base = xsrc + (mt * 16 + l16) * 136 + ks * 32 + (qd << 3);
          short8 af0 = *reinterpret_cast<const short8*>(base);
          short8 af1 = *reinterpret_cast<const short8*>(base + 136);
          short8 af2 = *reinterpret_cast<const short8*>(base + 272);
          acv = __builtin_amdgcn_mfma_f32_16x16x32_bf16(af0, w1r[0][ks], acv, 0, 0, 0);
          acv = __builtin_amdgcn_mfma_f32_16x16x32_bf16(af1, w1r[1][ks], acv, 0, 0, 0);
          acv = __builtin_amdgcn_mfma_f32_16x16x32_bf16(af2, w1r[2][ks], acv, 0, 0, 0);
          ach = __builtin_amdgcn_mfma_f32_16x16x32_bf16(af1, w1r[3][ks], ach, 0, 0, 0);
        }
#pragma unroll
        for (int r = 0; r < 4; ++r) {
          float kv = silu_f(silu_f(ach[r] + hpb_c) + (acv[r] + cvb_c) * sc_c + sh_c);
          kdst[(mt * 16 + qd * 4 + r) * 72 + c_lane] = f2bf(kv);
        }
      }
    }
    BARRIER();  // b2: kvb ready

    // ---- GEMM2, both tiles -> KVP ----
#pragma unroll 1
    for (int t = 0; t < 2; ++t) {
      const u16* ksrc = t ? kvb1 : kvb0;
      float* Kp = KVP + t * 40 * 129;
      floatx4 acc[3][2] = {};
#pragma unroll
      for (int mt = 0; mt < 3; ++mt) {
        short8 af[2];
#pragma unroll
        for (int ks = 0; ks < 2; ++ks)
          af[ks] = *reinterpret_cast<const short8*>(
              ksrc + (mt * 16 + l16) * 72 + ks * 32 + (qd << 3));
#pragma unroll
        for (int ntl = 0; ntl < 2; ++ntl)
#pragma unroll
          for (int ks = 0; ks < 2; ++ks)
            acc[mt][ntl] = __builtin_amdgcn_mfma_f32_16x16x32_bf16(
                af[ks], w2r[ntl][ks], acc[mt][ntl], 0, 0, 0);
      }
#pragma unroll
      for (int mt = 0; mt < 3; ++mt)
#pragma unroll
        for (int ntl = 0; ntl < 2; ++ntl)
#pragma unroll
          for (int r = 0; r < 4; ++r) {
            int row = mt * 16 + qd * 4 + r;
            if (row < 40)
              Kp[row * 129 + (wv * 2 + ntl) * 16 + l16] =
                  acc[mt][ntl][r] + (ntl ? kb1 : kb0);
          }
    }
    BARRIER();  // b3: KVP ready

    // ---- tail: fully wave-local. wave -> (tile tw, query qi) ----
    {
      const float* Kp = KVP + tw * 40 * 129;
      qh_s[wv * 64 + lane] = qhreg;  // in-wave publish (lgkmcnt only)
      float a4[4];
#pragma unroll
      for (int h = 0; h < 4; ++h) {
        float e = 0.f;
        if (lane < 40 && m_l > 0.f) {
          float s0 = 0.f, s1 = 0.f;
#pragma unroll
          for (int d = 0; d < 16; d += 2) {
            s0 += qh_s[wv * 64 + h * 16 + d] * Kp[lane * 129 + h * 16 + d];
            s1 += qh_s[wv * 64 + h * 16 + d + 1] * Kp[lane * 129 + h * 16 + d + 1];
          }
          e = __expf((s0 + s1) * 0.25f);
        }
        float sm = wave_sum(e);
        a4[h] = e / sm;
      }
#pragma unroll
      for (int h = 0; h < 4; ++h)
        if (lane < 40) a_s[(wv * 4 + h) * 40 + lane] = a4[h];
      // PV: lane = output dim d (0..63), 40-deep in two chains
      {
        int arow = wv * 4 + (lane >> 4);
        float v0 = 0.f, v1 = 0.f;
#pragma unroll
        for (int l = 0; l < 40; l += 2) {
          v0 += a_s[arow * 40 + l] * Kp[l * 129 + 64 + lane];
          v1 += a_s[arow * 40 + l + 1] * Kp[(l + 1) * 129 + 64 + lane];
        }
        op[wv * 64 + lane] = v0 + v1;
      }
      // out-proj + LN + store (in-wave reads of op)
      float acc0 = aob + qreg, acc1 = 0.f;
      const floatx4* wo4 = reinterpret_cast<const floatx4*>(woT);
#pragma unroll 8
      for (int k4 = 0; k4 < 16; ++k4) {
        floatx4 w4 = wo4[k4 * 64 + lane];
        floatx4 x4 = *reinterpret_cast<const floatx4*>(&op[wv * 64 + k4 * 4]);
        acc0 += x4[0] * w4[0] + x4[2] * w4[2];
        acc1 += x4[1] * w4[1] + x4[3] * w4[3];
      }
      float r = acc0 + acc1;
      float mean = wave_sum(r) * (1.f / 64.f);
      float dv = r - mean;
      float var = wave_sum(dv * dv) * (1.f / 64.f);
      float outv = dv * rsqrtf(var + EPS) * lng + lnb;
      ATT[((qi * 2 + s) * 8192 + b_w) * 64 + lane] = outv;
    }

    // ---- pack + rotate pipelined state ----
#pragma unroll
    for (int t = 0; t < 2; ++t)
#pragma unroll
      for (int j = 0; j < 3; ++j) {
        xr[t][j * 4 + 0] = pack2bf(pf[t][j][0], pf[t][j][1]);
        xr[t][j * 4 + 1] = pack2bf(pf[t][j][2], pf[t][j][3]);
        xr[t][j * 4 + 2] = pack2bf(pf[t][j][4], pf[t][j][5]);
        xr[t][j * 4 + 3] = pack2bf(pf[t][j][6], pf[t][j][7]);
        mkr[t][j] = mknew[t][j];
      }
    qreg = qn;
    qhreg = qhn;
    m_l = m_n;
  }
}

// ---------------------------------------------------------------------------
// head_kernel (r13 — unchanged control): 16 rows/block, aliased LDS arena.
// ---------------------------------------------------------------------------
__global__ __launch_bounds__(256) void head_kernel(
    const int* __restrict__ idA, const int* __restrict__ idB,
    const int* __restrict__ seedA, const int* __restrict__ seedB,
    const float* __restrict__ eloA, const float* __restrict__ eloB,
    const float* __restrict__ temb, const float* __restrict__ semb,
    const float* __restrict__ twT, const float* __restrict__ tw_b,
    const float* __restrict__ tbn_g, const float* __restrict__ tbn_b,
    const float* __restrict__ tbn_rm, const float* __restrict__ tbn_rv,
    const float* __restrict__ r1T, const float* __restrict__ r1_b,
    const float* __restrict__ r1bn_g, const float* __restrict__ r1bn_b,
    const float* __restrict__ r1bn_rm, const float* __restrict__ r1bn_rv,
    const float* __restrict__ r2T, const float* __restrict__ r2_b,
    const float* __restrict__ r2bn_g, const float* __restrict__ r2bn_b,
    const float* __restrict__ r2bn_rm, const float* __restrict__ r2bn_rv,
    const float* __restrict__ mu_w, const float* __restrict__ mu_b,
    const float* __restrict__ lv_w, const float* __restrict__ lv_b,
    const float* __restrict__ wl_w, const float* __restrict__ wl_b,
    const float* __restrict__ ATT, float* __restrict__ out) {
  __shared__ __align__(16) float smem[12416];  // 49664 B
  float* tv = smem;          // [2][16][260] (load + tower)
  float* rr = smem + 8320;   // [2][16][128]
  float* xv = smem;          // [16][256]    (after tower)
  float* xw = smem + 4096;   // [16][256]
  const int tid = threadIdx.x;
  const int b0 = blockIdx.x * 16;

  for (int idx = tid; idx < 2 * 16 * 260; idx += 256) {
    int k = idx % 260;
    int bi = (idx / 260) & 15;
    int team = idx / (260 * 16);
    int b = b0 + bi;
    float v;
    if (k < 96) v = temb[(team ? idB[b] : idA[b]) * 96 + k];
    else if (k < 128) v = semb[(team ? seedB[b] : seedA[b]) * 32 + (k - 96)];
    else if (k == 128) v = ((team ? eloB[b] : eloA[b]) - 1500.f) * (1.f / 400.f);
    else if (k < 193) v = ATT[((team * 2 + team) * 8192 + b) * 64 + (k - 129)];
    else if (k < 257) v = ATT[((team * 2 + (1 - team)) * 8192 + b) * 64 + (k - 193)];
    else v = 0.f;
    tv[(team * 16 + bi) * 260 + k] = v;
  }
  __syncthreads();

  {  // tower: 256 threads = 2 teams x 128 mids, 16 rows each
    int team = tid >> 7, mid = tid & 127;
    const floatx4* twv = reinterpret_cast<const floatx4*>(twT);
    float acc[16];
    float b_ = tw_b[mid];
#pragma unroll
    for (int bi = 0; bi < 16; ++bi) acc[bi] = b_;
#pragma unroll 2
    for (int k4 = 0; k4 < 65; ++k4) {
      floatx4 w4 = twv[k4 * 128 + mid];
#pragma unroll
      for (int bi = 0; bi < 16; ++bi) {
        floatx4 x4 = *reinterpret_cast<const floatx4*>(&tv[(team * 16 + bi) * 260 + k4 * 4]);
        acc[bi] += x4[0] * w4[0] + x4[1] * w4[1] + x4[2] * w4[2] + x4[3] * w4[3];
      }
    }
    float sc = rsqrtf(tbn_rv[mid] + EPS) * tbn_g[mid];
    float sh = tbn_b[mid] - tbn_rm[mid] * sc;
#pragma unroll
    for (int bi = 0; bi < 16; ++bi)
      rr[(team * 16 + bi) * 128 + mid] = silu_f(acc[bi] * sc + sh);
  }
  __syncthreads();
  {  // merge: xv overwrites tv region (all tv reads done before the barrier)
    int o = tid;
#pragma unroll
    for (int bi = 0; bi < 16; ++bi)
      xv[bi * 256 + o] = (o < 128)
                             ? (rr[bi * 128 + o] - rr[(16 + bi) * 128 + o])
                             : (rr[bi * 128 + o - 128] * rr[(16 + bi) * 128 + o - 128]);
  }
  __syncthreads();
  {  // r1: reads xv, writes xw
    int o = tid;
    const floatx4* r1v = reinterpret_cast<const floatx4*>(r1T);
    float acc[16];
    float b_ = r1_b[o];
#pragma unroll
    for (int bi = 0; bi < 16; ++bi) acc[bi] = b_;
#pragma unroll 2
    for (int k4 = 0; k4 < 64; ++k4) {
      floatx4 w4 = r1v[k4 * 256 + o];
#pragma unroll
      for (int bi = 0; bi < 16; ++bi) {
        floatx4 x4 = *reinterpret_cast<const floatx4*>(&xv[bi * 256 + k4 * 4]);
        acc[bi] += x4[0] * w4[0] + x4[1] * w4[1] + x4[2] * w4[2] + x4[3] * w4[3];
      }
    }
    float sc = rsqrtf(r1bn_rv[o] + EPS) * r1bn_g[o];
    float sh = r1bn_b[o] - r1bn_rm[o] * sc;
#pragma unroll
    for (int bi = 0; bi < 16; ++bi)
      xw[bi * 256 + o] = silu_f(acc[bi] * sc + sh) + xv[bi * 256 + o];
  }
  __syncthreads();
  {  // r2: reads xw, writes xv
    int o = tid;
    const floatx4* r2v = reinterpret_cast<const floatx4*>(r2T);
    float acc[16];
    float b_ = r2_b[o];
#pragma unroll
    for (int bi = 0; bi < 16; ++bi) acc[bi] = b_;
#pragma unroll 2
    for (int k4 = 0; k4 < 64; ++k4) {
      floatx4 w4 = r2v[k4 * 256 + o];
#pragma unroll
      for (int bi = 0; bi < 16; ++bi) {
        floatx4 x4 = *reinterpret_cast<const floatx4*>(&xw[bi * 256 + k4 * 4]);
        acc[bi] += x4[0] * w4[0] + x4[1] * w4[1] + x4[2] * w4[2] + x4[3] * w4[3];
      }
    }
    float sc = rsqrtf(r2bn_rv[o] + EPS) * r2bn_g[o];
    float sh = r2bn_b[o] - r2bn_rm[o] * sc;
#pragma unroll
    for (int bi = 0; bi < 16; ++bi)
      xv[bi * 256 + o] = silu_f(acc[bi] * sc + sh) + xw[bi * 256 + o];
  }
  __syncthreads();
  {  // heads: 256 threads = 16 rows x 16 outputs (mu 0..7, lv 0..7)
    int bi = tid >> 4, j = tid & 15;
    const float* wrow = (j < 8) ? (mu_w + j * 256) : (lv_w + (j - 8) * 256);
    const floatx4* wrow4 = reinterpret_cast<const floatx4*>(wrow);
    float acc = (j < 8) ? mu_b[j] : lv_b[j - 8];
#pragma unroll 4
    for (int k4 = 0; k4 < 64; ++k4) {
      floatx4 x4 = *reinterpret_cast<const floatx4*>(&xv[bi * 256 + k4 * 4]);
      floatx4 w4 = wrow4[k4];
      acc += x4[0] * w4[0] + x4[1] * w4[1] + x4[2] * w4[2] + x4[3] * w4[3];
    }
    int b = b0 + bi;
    if (j < 8) out[b * 8 + j] = acc;
    else out[65536 + b * 8 + (j - 8)] = acc;
    // win logit: 16 threads, one row each
    if (tid < 16) {
      const floatx4* wl4 = reinterpret_cast<const floatx4*>(wl_w);
      float acc2 = wl_b[0];
#pragma unroll 4
      for (int k4 = 0; k4 < 64; ++k4) {
        floatx4 x4 = *reinterpret_cast<const floatx4*>(&xv[tid * 256 + k4 * 4]);
        floatx4 w4 = wl4[k4];
        acc2 += x4[0] * w4[0] + x4[1] * w4[1] + x4[2] * w4[2] + x4[3] * w4[3];
      }
      out[131072 + b0 + tid] = acc2;
    }
  }
}

extern "C" void kernel_launch(void* const* d_in, const int* in_sizes, int n_in,
                              void* d_out, int out_size, void* d_ws, size_t ws_size,
                              hipStream_t stream) {
  const int* idA = (const int*)d_in[0];
  const int* idB = (const int*)d_in[1];
  const int* seedA = (const int*)d_in[2];
  const int* seedB = (const int*)d_in[3];
  const float* eloA = (const float*)d_in[4];
  const float* eloB = (const float*)d_in[5];
  const float* hnA = (const float*)d_in[6];
  const float* hnB = (const float*)d_in[7];
  const int* oppA = (const int*)d_in[8];
  const int* oppB = (const int*)d_in[9];
  const float* mskA = (const float*)d_in[10];
  const float* mskB = (const float*)d_in[11];
  const float* temb = (const float*)d_in[12];
  const float* semb = (const float*)d_in[13];
  const float* conv_w = (const float*)d_in[14];
  const float* conv_b = (const float*)d_in[15];
  const float* cbn_g = (const float*)d_in[16];
  const float* cbn_b = (const float*)d_in[17];
  const float* cbn_rm = (const float*)d_in[18];
  const float* cbn_rv = (const float*)d_in[19];
  const float* hp_w = (const float*)d_in[20];
  const float* hp_b = (const float*)d_in[21];
  const float* qp_w = (const float*)d_in[22];
  const float* qp_b = (const float*)d_in[23];
  const float* attn_in_w = (const float*)d_in[24];
  const float* attn_in_b = (const float*)d_in[25];
  const float* attn_out_w = (const float*)d_in[26];
  const float* attn_out_b = (const float*)d_in[27];
  const float* ln_g = (const float*)d_in[28];
  const float* ln_b = (const float*)d_in[29];
  const float* tw_w = (const float*)d_in[30];
  const float* tw_b = (const float*)d_in[31];
  const float* tbn_g = (const float*)d_in[32];
  const float* tbn_b = (const float*)d_in[33];
  const float* tbn_rm = (const float*)d_in[34];
  const float* tbn_rv = (const float*)d_in[35];
  const float* r1_w = (const float*)d_in[36];
  const float* r1_b = (const float*)d_in[37];
  const float* r1bn_g = (const float*)d_in[38];
  const float* r1bn_b = (const float*)d_in[39];
  const float* r1bn_rm = (const float*)d_in[40];
  const float* r1bn_rv = (const float*)d_in[41];
  const float* r2_w = (const float*)d_in[42];
  const float* r2_b = (const float*)d_in[43];
  const float* r2bn_g = (const float*)d_in[44];
  const float* r2bn_b = (const float*)d_in[45];
  const float* r2bn_rm = (const float*)d_in[46];
  const float* r2bn_rv = (const float*)d_in[47];
  const float* mu_w = (const float*)d_in[48];
  const float* mu_b = (const float*)d_in[49];
  const float* lv_w = (const float*)d_in[50];
  const float* lv_b = (const float*)d_in[51];
  const float* wl_w = (const float*)d_in[52];
  const float* wl_b = (const float*)d_in[53];

  char* ws = (char*)d_ws;
  u16* w1f = (u16*)(ws + 0);             //  65536 B
  u16* w2f = (u16*)(ws + 65536);         //  16384 B
  float* woT = (float*)(ws + 81920);     //  16384 B (only 4096 floats used)
  float* Qg = (float*)(ws + 98304);      // 102400 B
  float* QHg = (float*)(ws + 200704);    // 102400 B
  float* twT = (float*)(ws + 303104);    // 133120 B
  float* r1T = (float*)(ws + 436224);    // 262144 B
  float* r2T = (float*)(ws + 698368);    // 262144 B
  float* ATT = (float*)(ws + 960512);    // 8388608 B

  prep_kernel<<<256, 256, 0, stream>>>(hp_w, conv_w, attn_in_w, attn_out_w,
                                       tw_w, r1_w, r2_w,
                                       w1f, w2f, woT, twT, r1T, r2T);
  team_kernel<<<400, 64, 0, stream>>>(temb, qp_w, qp_b, attn_in_w, attn_in_b, Qg, QHg);
  attn_kernel<<<2048, 256, 0, stream>>>(idA, idB, hnA, hnB, oppA, oppB, mskA, mskB,
                                        temb, conv_b, cbn_g, cbn_b, cbn_rm, cbn_rv,
                                        hp_b, attn_in_b, attn_out_b, ln_g, ln_b,
                                        w1f, w2f, woT, Qg, QHg, ATT);
  head_kernel<<<512, 256, 0, stream>>>(idA, idB, seedA, seedB, eloA, eloB, temb, semb,
                                       twT, tw_b, tbn_g, tbn_b, tbn_rm, tbn_rv,
                                       r1T, r1_b, r1bn_g, r1bn_b, r1bn_rm, r1bn_rv,
                                       r2T, r2_b, r2bn_g, r2bn_b, r2bn_rm, r2bn_rv,
                                       mu_w, mu_b, lv_w, lv_b, wl_w, wl_b,
                                       ATT, (float*)d_out);
}

// Round 12
// 539.683 us; speedup vs baseline: 1.0136x; 1.0136x over previous
//
#include <hip/hip_runtime.h>
#include <stdint.h>

#define EPS 1e-5f

typedef __attribute__((ext_vector_type(8))) short short8;
typedef __attribute__((ext_vector_type(4))) float floatx4;
typedef __attribute__((ext_vector_type(4))) unsigned uintx4;
typedef unsigned short u16;

__device__ __forceinline__ u16 f2bf(float f) {
  unsigned u = __builtin_bit_cast(unsigned, f);
  u += 0x7fffu + ((u >> 16) & 1u);
  return (u16)(u >> 16);
}
__device__ __forceinline__ float bf2f(u16 h) {
  return __builtin_bit_cast(float, (unsigned)h << 16);
}
__device__ __forceinline__ unsigned pack2bf(float a, float b) {
  return (unsigned)f2bf(a) | ((unsigned)f2bf(b) << 16);
}
__device__ __forceinline__ float silu_f(float x) { return x / (1.f + __expf(-x)); }
__device__ __forceinline__ float wave_sum(float x) {
  for (int off = 32; off > 0; off >>= 1) x += __shfl_xor(x, off);
  return x;
}

// LDS-only barrier: drains ds ops (lgkmcnt) but NOT global loads (vmcnt).
// All cross-wave deps in attn_kernel are through LDS; global loads are
// register-consumed (compiler inserts vmcnt waits at each use). Removes the
// structural s_waitcnt vmcnt(0) that __syncthreads emits before s_barrier,
// letting the prefetch-slot loads stay in flight past barrier2 until the
// post-barrier2 pack consumes them (r9-identified mechanism, here isolated
// from r19's confounded tail restructure).
#define BARRIER()                                         \
  do {                                                    \
    asm volatile("s_waitcnt lgkmcnt(0)" ::: "memory");    \
    __builtin_amdgcn_s_barrier();                         \
  } while (0)

// ---------------------------------------------------------------------------
// prep: swizzle weights into MFMA fragment order.
// w1f layout (conv-fold): [tap 0..3][nt 0..3][ks 0..3][lane][8]; tap 0..2 =
// conv taps, tap 3 = hp. woT packed [k4][64][4] for coalesced dwordx4.
// ---------------------------------------------------------------------------
__global__ void prep_kernel(const float* __restrict__ hp_w, const float* __restrict__ conv_w,
                            const float* __restrict__ attn_in_w,
                            const float* __restrict__ attn_out_w,
                            const float* __restrict__ tw_w, const float* __restrict__ r1_w,
                            const float* __restrict__ r2_w,
                            u16* __restrict__ w1f, u16* __restrict__ w2f,
                            float* __restrict__ woT,
                            float* __restrict__ twT, float* __restrict__ r1T,
                            float* __restrict__ r2T) {
  int t = blockIdx.x * 256 + threadIdx.x;  // 0..65535
  if (t < 32768) {
    int j = t & 7, lane = (t >> 3) & 63, ks = (t >> 9) & 3, nt = (t >> 11) & 3, tp = t >> 13;
    int k = ks * 32 + ((lane >> 4) << 3) + j;
    int c = nt * 16 + (lane & 15);
    float v = (tp == 3) ? hp_w[c * 128 + k] : conv_w[c * 384 + k * 3 + tp];
    w1f[t] = f2bf(v);
  }
  if (t < 8192) {
    int j = t & 7, lane = (t >> 3) & 63, ks = (t >> 9) & 1, nt = t >> 10;
    int k = ks * 32 + ((lane >> 4) << 3) + j;
    int n = nt * 16 + (lane & 15);
    w2f[t] = f2bf(attn_in_w[(64 + n) * 64 + k]);
  }
  if (t < 1024) {  // woT[(k4*64+j)*4+i] = attn_out_w[j][k4*4+i]
    int j = t & 63, k4 = t >> 6;
#pragma unroll
    for (int i = 0; i < 4; ++i)
      woT[(k4 * 64 + j) * 4 + i] = attn_out_w[j * 64 + k4 * 4 + i];
  }
  if (t < 8320) {  // twT[k4 0..64][mid 0..127][4]; k=257..259 zero-padded
    int mid = t & 127, k4 = t >> 7;
#pragma unroll
    for (int i = 0; i < 4; ++i) {
      int k = k4 * 4 + i;
      twT[t * 4 + i] = (k < 257) ? tw_w[mid * 257 + k] : 0.f;
    }
  }
  if (t < 16384) {  // r1T/r2T[k4 0..63][o 0..255][4]
    int o = t & 255, k4 = t >> 8;
#pragma unroll
    for (int i = 0; i < 4; ++i) {
      r1T[t * 4 + i] = r1_w[o * 256 + k4 * 4 + i];
      r2T[t * 4 + i] = r2_w[o * 256 + k4 * 4 + i];
    }
  }
}

// ---------------------------------------------------------------------------
// team_kernel: per-team q = temb[t]@qp_w.T + qp_b ; qh = q@wq.T + bq
// ---------------------------------------------------------------------------
__global__ __launch_bounds__(64) void team_kernel(
    const float* __restrict__ temb, const float* __restrict__ qp_w,
    const float* __restrict__ qp_b, const float* __restrict__ attn_in_w,
    const float* __restrict__ attn_in_b,
    float* __restrict__ Qg, float* __restrict__ QHg) {
  __shared__ float e[96];
  __shared__ float qv[64];
  const int t = blockIdx.x;   // team id 0..399
  const int o = threadIdx.x;  // 0..63
  for (int i = o; i < 96; i += 64) e[i] = temb[t * 96 + i];
  __syncthreads();
  float acc = qp_b[o];
  for (int k = 0; k < 96; ++k) acc += e[k] * qp_w[o * 96 + k];
  qv[o] = acc;
  Qg[t * 64 + o] = acc;
  __syncthreads();
  float acc2 = attn_in_b[o];
  for (int k = 0; k < 64; ++k) acc2 += qv[k] * attn_in_w[o * 64 + k];
  QHg[t * 64 + o] = acc2;
}

// ---------------------------------------------------------------------------
// attn_kernel (r20 = r18 + lgkmcnt-only barriers). r18 structure (best,
// 529.9 e2e): index-load software pipeline, 4 barriers/unit, r8 tail split
// (2 heads/wave scores, PV own-dims in-wave, out-proj waves 0,1). The ONLY
// change vs r18: all __syncthreads -> BARRIER() (lgkm-only). r19 bundled
// this with a tail restructure that undid the r8 split and regressed;
// here it is isolated on the proven-best structure.
// Diagnostics: everything identical to r18 except possibly dur.
// ---------------------------------------------------------------------------
__global__ __launch_bounds__(256, 2) void attn_kernel(
    const int* __restrict__ idA, const int* __restrict__ idB,
    const float* __restrict__ hnA, const float* __restrict__ hnB,
    const int* __restrict__ oppA, const int* __restrict__ oppB,
    const float* __restrict__ mskA, const float* __restrict__ mskB,
    const float* __restrict__ temb, const float* __restrict__ conv_b,
    const float* __restrict__ cbn_g, const float* __restrict__ cbn_b,
    const float* __restrict__ cbn_rm, const float* __restrict__ cbn_rv,
    const float* __restrict__ hp_b,
    const float* __restrict__ attn_in_b, const float* __restrict__ attn_out_b,
    const float* __restrict__ ln_g, const float* __restrict__ ln_b,
    const u16* __restrict__ w1f, const u16* __restrict__ w2f,
    const float* __restrict__ woT,
    const float* __restrict__ Qg, const float* __restrict__ QHg,
    float* __restrict__ ATT) {
  // unified arena, 38976 B:
  //   [0,      11424) xs  : u16 [42][136]
  //   [11424,  18336) kvb : u16 [48][72]  (tail aliases a_s/op here)
  //   [18336,  38976) KVP : f32 [40][129]
  __shared__ __align__(16) u16 arena[19488];
  __shared__ __align__(16) float qh_s[2 * 64];
  u16* xs = arena;
  u16* kvb = arena + 5712;
  float* KVP = (float*)(arena + 9168);
  float* a_s = (float*)(arena + 5712);           // [8][40]
  float* op = a_s + 8 * 40;                      // [2][64] PV outputs

  const int tid = threadIdx.x;
  const int lane = tid & 63;
  const int wv = tid >> 6;
  const int qd = lane >> 4;
  const int l16 = lane & 15;
  const int qw = wv >> 1;    // tail: which q this wave serves
  const int hw = wv & 1;     // tail: which head-pair / dim-half

  const int c_lane = wv * 16 + l16;
  const float sc_c = rsqrtf(cbn_rv[c_lane] + EPS) * cbn_g[c_lane];
  const float sh_c = cbn_b[c_lane] - cbn_rm[c_lane] * sc_c;
  const float hpb_c = hp_b[c_lane];
  const float cvb_c = conv_b[c_lane];
  const float lng = ln_g[lane], lnb = ln_b[lane];
  const float aob = attn_out_b[lane];
  const float kb0 = attn_in_b[64 + (wv * 2 + 0) * 16 + l16];
  const float kb1 = attn_in_b[64 + (wv * 2 + 1) * 16 + l16];

  if (tid < 136) {
    xs[tid] = 0;
    xs[41 * 136 + tid] = 0;
  }

  short8 w1r[4][4];  // [tap: 0..2 conv, 3 hp][ks]
#pragma unroll
  for (int tp = 0; tp < 4; ++tp)
#pragma unroll
    for (int ks = 0; ks < 4; ++ks)
      w1r[tp][ks] = *reinterpret_cast<const short8*>(
          w1f + (((tp * 4 + wv) * 4 + ks) * 64 + lane) * 8);
  short8 w2r[2][2];
#pragma unroll
  for (int ntl = 0; ntl < 2; ++ntl)
#pragma unroll
    for (int ks = 0; ks < 2; ++ks)
      w2r[ntl][ks] = *reinterpret_cast<const short8*>(
          w2f + (((wv * 2 + ntl) * 2 + ks) * 64 + lane) * 8);

  // ---- unit-0 x data (one-time dependent loads, drained pre-loop) ----
  unsigned xr[12];
  float mkr[3];
  {
    int np = blockIdx.x;
    int pb = np >> 1;
    const float* phn = (np & 1) ? hnB : hnA;
    const int* popp = (np & 1) ? oppB : oppA;
    const float* pmsk = (np & 1) ? mskB : mskA;
#pragma unroll
    for (int j = 0; j < 3; ++j) {
      int sidx = j * 256 + tid;
      int srow = sidx >> 4, scg = sidx & 15;
      if (srow < 40) {
        int mrow = pb * 40 + srow;
        mkr[j] = pmsk[mrow];
        const float* p = (scg < 4)
                             ? phn + (size_t)mrow * 32 + scg * 8
                             : temb + (size_t)popp[mrow] * 96 + (scg * 8 - 32);
        floatx4 f0 = *reinterpret_cast<const floatx4*>(p);
        floatx4 f1 = *reinterpret_cast<const floatx4*>(p + 4);
        xr[j * 4 + 0] = pack2bf(f0[0], f0[1]);
        xr[j * 4 + 1] = pack2bf(f0[2], f0[3]);
        xr[j * 4 + 2] = pack2bf(f1[0], f1[1]);
        xr[j * 4 + 3] = pack2bf(f1[2], f1[3]);
      } else {
        mkr[j] = 0.f;
        xr[j * 4 + 0] = xr[j * 4 + 1] = xr[j * 4 + 2] = xr[j * 4 + 3] = 0u;
      }
    }
  }

  // ---- unit-0 q/mask + pipelined indices for unit 1 ----
  float qreg = 0.f, qhreg = 0.f, m_l = 0.f;
  int idn = 0;       // team id for unit 1 (wv<2)
  int oppn[3];       // popp row values for unit 1 staging
  {
    int b0i = blockIdx.x >> 1, s0 = blockIdx.x & 1;
    if (lane < 40) m_l = (s0 ? mskB : mskA)[b0i * 40 + lane];
    if (wv < 2) {
      int id0 = wv ? idB[b0i] : idA[b0i];
      qreg = Qg[id0 * 64 + lane];
      qhreg = QHg[id0 * 64 + lane];
      idn = wv ? idB[b0i + 1024] : idA[b0i + 1024];
    }
    int np1 = blockIdx.x + 2048;
    int pb1 = np1 >> 1;
    const int* popp1 = (np1 & 1) ? oppB : oppA;
#pragma unroll
    for (int j = 0; j < 3; ++j) {
      int srow = (j * 256 + tid) >> 4;
      oppn[j] = (srow < 40) ? popp1[pb1 * 40 + srow] : 0;
    }
  }
  BARRIER();  // pad-zero visible (LDS); prologue loads wait at use

#pragma unroll 1
  for (int it = 0; it < 8; ++it) {
    int pair = blockIdx.x + it * 2048;
    int b = pair >> 1, s = pair & 1;

    // stage x rows 1..40 (rows 0/41 stay zero)
#pragma unroll
    for (int j = 0; j < 3; ++j) {
      int sidx = j * 256 + tid;
      int srow = sidx >> 4;
      if (srow < 40) {
        bool keep = mkr[j] != 0.f;
        uintx4 v;
        v[0] = keep ? xr[j * 4 + 0] : 0u;
        v[1] = keep ? xr[j * 4 + 1] : 0u;
        v[2] = keep ? xr[j * 4 + 2] : 0u;
        v[3] = keep ? xr[j * 4 + 3] : 0u;
        *reinterpret_cast<uintx4*>(xs + (srow + 1) * 136 + (sidx & 15) * 8) = v;
      }
    }
    BARRIER();  // barrier1: xs ready

    // ---- prefetch slot: ALL loads independent, indices resident ----
    float pf[3][8];
    float mknew[3];
    float m_n = 0.f, qn = 0.f, qhn = 0.f;
    int idn2 = 0;
    {
      int np = (it < 7) ? pair + 2048 : pair;
      int pb = np >> 1;
      const float* phn = (np & 1) ? hnB : hnA;
      const float* pmsk = (np & 1) ? mskB : mskA;
#pragma unroll
      for (int j = 0; j < 3; ++j) {
        int sidx = j * 256 + tid;
        int srow = sidx >> 4, scg = sidx & 15;
        if (srow < 40) {
          int mrow = pb * 40 + srow;
          mknew[j] = pmsk[mrow];
          const float* p = (scg < 4)
                               ? phn + (size_t)mrow * 32 + scg * 8
                               : temb + (size_t)oppn[j] * 96 + (scg * 8 - 32);
          *reinterpret_cast<floatx4*>(&pf[j][0]) = *reinterpret_cast<const floatx4*>(p);
          *reinterpret_cast<floatx4*>(&pf[j][4]) = *reinterpret_cast<const floatx4*>(p + 4);
        } else {
          mknew[j] = 0.f;
#pragma unroll
          for (int q = 0; q < 8; ++q) pf[j][q] = 0.f;
        }
      }
      if (lane < 40) m_n = pmsk[pb * 40 + lane];   // tail mask for i+1
      if (wv < 2) {                                 // q gathers, idn resident
        qn = Qg[idn * 64 + lane];
        qhn = QHg[idn * 64 + lane];
      }
      // index loads for unit i+2 (direct, no deps)
      int np2 = (it < 6) ? pair + 4096 : pair;
      int pb2 = np2 >> 1;
      const int* popp2 = (np2 & 1) ? oppB : oppA;
#pragma unroll
      for (int j = 0; j < 3; ++j) {
        int srow = (j * 256 + tid) >> 4;
        oppn[j] = (srow < 40) ? popp2[pb2 * 40 + srow] : 0;
      }
      if (wv < 2) idn2 = wv ? idB[pb2] : idA[pb2];
    }

    // ---- GEMM1' conv-fold ----
#pragma unroll 1
    for (int mt = 0; mt < 3; ++mt) {
      floatx4 ach = {0.f, 0.f, 0.f, 0.f};
      floatx4 acv = {0.f, 0.f, 0.f, 0.f};
#pragma unroll
      for (int ks = 0; ks < 4; ++ks) {
        const u16* base = xs + (mt * 16 + l16) * 136 + ks * 32 + (qd << 3);
        short8 af0 = *reinterpret_cast<const short8*>(base);
        short8 af1 = *reinterpret_cast<const short8*>(base + 136);
        short8 af2 = *reinterpret_cast<const short8*>(base + 272);
        acv = __builtin_amdgcn_mfma_f32_16x16x32_bf16(af0, w1r[0][ks], acv, 0, 0, 0);
        acv = __builtin_amdgcn_mfma_f32_16x16x32_bf16(af1, w1r[1][ks], acv, 0, 0, 0);
        acv = __builtin_amdgcn_mfma_f32_16x16x32_bf16(af2, w1r[2][ks], acv, 0, 0, 0);
        ach = __builtin_amdgcn_mfma_f32_16x16x32_bf16(af1, w1r[3][ks], ach, 0, 0, 0);
      }
#pragma unroll
      for (int r = 0; r < 4; ++r) {
        float kv = silu_f(silu_f(ach[r] + hpb_c) + (acv[r] + cvb_c) * sc_c + sh_c);
        kvb[(mt * 16 + qd * 4 + r) * 72 + c_lane] = f2bf(kv);
      }
    }
    if (wv < 2) qh_s[wv * 64 + lane] = qhreg;
    BARRIER();  // barrier2: kvb + qh_s ready; prefetch loads still in flight

    // repack prefetched x (compiler places vmcnt waits here, at first use —
    // the loads had staging+GEMM1+GEMM2-issue to land)
#pragma unroll
    for (int j = 0; j < 3; ++j) {
      xr[j * 4 + 0] = pack2bf(pf[j][0], pf[j][1]);
      xr[j * 4 + 1] = pack2bf(pf[j][2], pf[j][3]);
      xr[j * 4 + 2] = pack2bf(pf[j][4], pf[j][5]);
      xr[j * 4 + 3] = pack2bf(pf[j][6], pf[j][7]);
      mkr[j] = mknew[j];
    }

    {
      floatx4 acc[3][2] = {};
#pragma unroll
      for (int mt = 0; mt < 3; ++mt) {
        short8 af[2];
#pragma unroll
        for (int ks = 0; ks < 2; ++ks)
          af[ks] = *reinterpret_cast<const short8*>(
              kvb + (mt * 16 + l16) * 72 + ks * 32 + (qd << 3));
#pragma unroll
        for (int ntl = 0; ntl < 2; ++ntl)
#pragma unroll
          for (int ks = 0; ks < 2; ++ks)
            acc[mt][ntl] = __builtin_amdgcn_mfma_f32_16x16x32_bf16(
                af[ks], w2r[ntl][ks], acc[mt][ntl], 0, 0, 0);
      }
#pragma unroll
      for (int mt = 0; mt < 3; ++mt)
#pragma unroll
        for (int ntl = 0; ntl < 2; ++ntl)
#pragma unroll
          for (int r = 0; r < 4; ++r) {
            int row = mt * 16 + qd * 4 + r;
            if (row < 40)
              KVP[row * 129 + (wv * 2 + ntl) * 16 + l16] =
                  acc[mt][ntl][r] + (ntl ? kb1 : kb0);
          }
    }
    BARRIER();  // barrier3: KVP ready

    // ---- T2: scores — wave (qw,hw) computes heads hw*2, hw*2+1 for q=qw
    {
      float a2[2];
#pragma unroll
      for (int hh = 0; hh < 2; ++hh) {
        int h = hw * 2 + hh;
        float e = 0.f;
        if (lane < 40 && m_l > 0.f) {
          float s0 = 0.f, s1 = 0.f;
#pragma unroll
          for (int d = 0; d < 16; d += 2) {
            s0 += qh_s[qw * 64 + h * 16 + d] * KVP[lane * 129 + h * 16 + d];
            s1 += qh_s[qw * 64 + h * 16 + d + 1] * KVP[lane * 129 + h * 16 + d + 1];
          }
          e = __expf((s0 + s1) * 0.25f);
        }
        float sm = wave_sum(e);
        a2[hh] = e / sm;
      }
      if (lane < 40) {
        a_s[(qw * 4 + hw * 2 + 0) * 40 + lane] = a2[0];
        a_s[(qw * 4 + hw * 2 + 1) * 40 + lane] = a2[1];
      }
    }

    // ---- T3 (no barrier): PV for OWN heads' dims — d = hw*32+(lane&31),
    // l-half by lane>>5, combined via shfl_xor(32). Reads only a_s rows
    // this wave wrote (in-wave LDS ordering, compiler lgkmcnt).
    {
      int d = hw * 32 + (lane & 31);
      int arow = qw * 4 + (d >> 4);
      int l0 = (lane >> 5) * 20;
      float v0 = 0.f, v1 = 0.f;
#pragma unroll
      for (int li = 0; li < 20; li += 2) {
        int l = l0 + li;
        v0 += a_s[arow * 40 + l] * KVP[l * 129 + 64 + d];
        v1 += a_s[arow * 40 + l + 1] * KVP[(l + 1) * 129 + 64 + d];
      }
      float v = v0 + v1;
      v += __shfl_xor(v, 32);
      if (lane < 32) op[qw * 64 + d] = v;
    }
    BARRIER();  // barrier4: op ready for out-proj

    // ---- T4+T5: full out-proj + LN (waves 0,1); waves 2,3 run ahead ----
    if (wv < 2) {
      int qi = wv;
      float acc0 = aob + qreg, acc1 = 0.f;
      const floatx4* wo4 = reinterpret_cast<const floatx4*>(woT);
#pragma unroll 8
      for (int k4 = 0; k4 < 16; ++k4) {
        floatx4 w4 = wo4[k4 * 64 + lane];
        floatx4 x4 = *reinterpret_cast<const floatx4*>(&op[qi * 64 + k4 * 4]);
        acc0 += x4[0] * w4[0] + x4[2] * w4[2];
        acc1 += x4[1] * w4[1] + x4[3] * w4[3];
      }
      float r = acc0 + acc1;
      float mean = wave_sum(r) * (1.f / 64.f);
      float dv = r - mean;
      float var = wave_sum(dv * dv) * (1.f / 64.f);
      float outv = dv * rsqrtf(var + EPS) * lng + lnb;
      ATT[((qi * 2 + s) * 8192 + b) * 64 + lane] = outv;
    }

    // rotate pipelined state (registers only, no loads)
    qreg = qn;
    qhreg = qhn;
    m_l = m_n;
    idn = idn2;
  }
}

// ---------------------------------------------------------------------------
// head_kernel (r13 — unchanged control): 16 rows/block, aliased LDS arena.
// ---------------------------------------------------------------------------
__global__ __launch_bounds__(256) void head_kernel(
    const int* __restrict__ idA, const int* __restrict__ idB,
    const int* __restrict__ seedA, const int* __restrict__ seedB,
    const float* __restrict__ eloA, const float* __restrict__ eloB,
    const float* __restrict__ temb, const float* __restrict__ semb,
    const float* __restrict__ twT, const float* __restrict__ tw_b,
    const float* __restrict__ tbn_g, const float* __restrict__ tbn_b,
    const float* __restrict__ tbn_rm, const float* __restrict__ tbn_rv,
    const float* __restrict__ r1T, const float* __restrict__ r1_b,
    const float* __restrict__ r1bn_g, const float* __restrict__ r1bn_b,
    const float* __restrict__ r1bn_rm, const float* __restrict__ r1bn_rv,
    const float* __restrict__ r2T, const float* __restrict__ r2_b,
    const float* __restrict__ r2bn_g, const float* __restrict__ r2bn_b,
    const float* __restrict__ r2bn_rm, const float* __restrict__ r2bn_rv,
    const float* __restrict__ mu_w, const float* __restrict__ mu_b,
    const float* __restrict__ lv_w, const float* __restrict__ lv_b,
    const float* __restrict__ wl_w, const float* __restrict__ wl_b,
    const float* __restrict__ ATT, float* __restrict__ out) {
  __shared__ __align__(16) float smem[12416];  // 49664 B
  float* tv = smem;          // [2][16][260] (load + tower)
  float* rr = smem + 8320;   // [2][16][128]
  float* xv = smem;          // [16][256]    (after tower)
  float* xw = smem + 4096;   // [16][256]
  const int tid = threadIdx.x;
  const int b0 = blockIdx.x * 16;

  for (int idx = tid; idx < 2 * 16 * 260; idx += 256) {
    int k = idx % 260;
    int bi = (idx / 260) & 15;
    int team = idx / (260 * 16);
    int b = b0 + bi;
    float v;
    if (k < 96) v = temb[(team ? idB[b] : idA[b]) * 96 + k];
    else if (k < 128) v = semb[(team ? seedB[b] : seedA[b]) * 32 + (k - 96)];
    else if (k == 128) v = ((team ? eloB[b] : eloA[b]) - 1500.f) * (1.f / 400.f);
    else if (k < 193) v = ATT[((team * 2 + team) * 8192 + b) * 64 + (k - 129)];
    else if (k < 257) v = ATT[((team * 2 + (1 - team)) * 8192 + b) * 64 + (k - 193)];
    else v = 0.f;
    tv[(team * 16 + bi) * 260 + k] = v;
  }
  __syncthreads();

  {  // tower: 256 threads = 2 teams x 128 mids, 16 rows each
    int team = tid >> 7, mid = tid & 127;
    const floatx4* twv = reinterpret_cast<const floatx4*>(twT);
    float acc[16];
    float b_ = tw_b[mid];
#pragma unroll
    for (int bi = 0; bi < 16; ++bi) acc[bi] = b_;
#pragma unroll 2
    for (int k4 = 0; k4 < 65; ++k4) {
      floatx4 w4 = twv[k4 * 128 + mid];
#pragma unroll
      for (int bi = 0; bi < 16; ++bi) {
        floatx4 x4 = *reinterpret_cast<const floatx4*>(&tv[(team * 16 + bi) * 260 + k4 * 4]);
        acc[bi] += x4[0] * w4[0] + x4[1] * w4[1] + x4[2] * w4[2] + x4[3] * w4[3];
      }
    }
    float sc = rsqrtf(tbn_rv[mid] + EPS) * tbn_g[mid];
    float sh = tbn_b[mid] - tbn_rm[mid] * sc;
#pragma unroll
    for (int bi = 0; bi < 16; ++bi)
      rr[(team * 16 + bi) * 128 + mid] = silu_f(acc[bi] * sc + sh);
  }
  __syncthreads();
  {  // merge: xv overwrites tv region (all tv reads done before the barrier)
    int o = tid;
#pragma unroll
    for (int bi = 0; bi < 16; ++bi)
      xv[bi * 256 + o] = (o < 128)
                             ? (rr[bi * 128 + o] - rr[(16 + bi) * 128 + o])
                             : (rr[bi * 128 + o - 128] * rr[(16 + bi) * 128 + o - 128]);
  }
  __syncthreads();
  {  // r1: reads xv, writes xw
    int o = tid;
    const floatx4* r1v = reinterpret_cast<const floatx4*>(r1T);
    float acc[16];
    float b_ = r1_b[o];
#pragma unroll
    for (int bi = 0; bi < 16; ++bi) acc[bi] = b_;
#pragma unroll 2
    for (int k4 = 0; k4 < 64; ++k4) {
      floatx4 w4 = r1v[k4 * 256 + o];
#pragma unroll
      for (int bi = 0; bi < 16; ++bi) {
        floatx4 x4 = *reinterpret_cast<const floatx4*>(&xv[bi * 256 + k4 * 4]);
        acc[bi] += x4[0] * w4[0] + x4[1] * w4[1] + x4[2] * w4[2] + x4[3] * w4[3];
      }
    }
    float sc = rsqrtf(r1bn_rv[o] + EPS) * r1bn_g[o];
    float sh = r1bn_b[o] - r1bn_rm[o] * sc;
#pragma unroll
    for (int bi = 0; bi < 16; ++bi)
      xw[bi * 256 + o] = silu_f(acc[bi] * sc + sh) + xv[bi * 256 + o];
  }
  __syncthreads();
  {  // r2: reads xw, writes xv
    int o = tid;
    const floatx4* r2v = reinterpret_cast<const floatx4*>(r2T);
    float acc[16];
    float b_ = r2_b[o];
#pragma unroll
    for (int bi = 0; bi < 16; ++bi) acc[bi] = b_;
#pragma unroll 2
    for (int k4 = 0; k4 < 64; ++k4) {
      floatx4 w4 = r2v[k4 * 256 + o];
#pragma unroll
      for (int bi = 0; bi < 16; ++bi) {
        floatx4 x4 = *reinterpret_cast<const floatx4*>(&xw[bi * 256 + k4 * 4]);
        acc[bi] += x4[0] * w4[0] + x4[1] * w4[1] + x4[2] * w4[2] + x4[3] * w4[3];
      }
    }
    float sc = rsqrtf(r2bn_rv[o] + EPS) * r2bn_g[o];
    float sh = r2bn_b[o] - r2bn_rm[o] * sc;
#pragma unroll
    for (int bi = 0; bi < 16; ++bi)
      xv[bi * 256 + o] = silu_f(acc[bi] * sc + sh) + xw[bi * 256 + o];
  }
  __syncthreads();
  {  // heads: 256 threads = 16 rows x 16 outputs (mu 0..7, lv 0..7)
    int bi = tid >> 4, j = tid & 15;
    const float* wrow = (j < 8) ? (mu_w + j * 256) : (lv_w + (j - 8) * 256);
    const floatx4* wrow4 = reinterpret_cast<const floatx4*>(wrow);
    float acc = (j < 8) ? mu_b[j] : lv_b[j - 8];
#pragma unroll 4
    for (int k4 = 0; k4 < 64; ++k4) {
      floatx4 x4 = *reinterpret_cast<const floatx4*>(&xv[bi * 256 + k4 * 4]);
      floatx4 w4 = wrow4[k4];
      acc += x4[0] * w4[0] + x4[1] * w4[1] + x4[2] * w4[2] + x4[3] * w4[3];
    }
    int b = b0 + bi;
    if (j < 8) out[b * 8 + j] = acc;
    else out[65536 + b * 8 + (j - 8)] = acc;
    // win logit: 16 threads, one row each
    if (tid < 16) {
      const floatx4* wl4 = reinterpret_cast<const floatx4*>(wl_w);
      float acc2 = wl_b[0];
#pragma unroll 4
      for (int k4 = 0; k4 < 64; ++k4) {
        floatx4 x4 = *reinterpret_cast<const floatx4*>(&xv[tid * 256 + k4 * 4]);
        floatx4 w4 = wl4[k4];
        acc2 += x4[0] * w4[0] + x4[1] * w4[1] + x4[2] * w4[2] + x4[3] * w4[3];
      }
      out[131072 + b0 + tid] = acc2;
    }
  }
}

extern "C" void kernel_launch(void* const* d_in, const int* in_sizes, int n_in,
                              void* d_out, int out_size, void* d_ws, size_t ws_size,
                              hipStream_t stream) {
  const int* idA = (const int*)d_in[0];
  const int* idB = (const int*)d_in[1];
  const int* seedA = (const int*)d_in[2];
  const int* seedB = (const int*)d_in[3];
  const float* eloA = (const float*)d_in[4];
  const float* eloB = (const float*)d_in[5];
  const float* hnA = (const float*)d_in[6];
  const float* hnB = (const float*)d_in[7];
  const int* oppA = (const int*)d_in[8];
  const int* oppB = (const int*)d_in[9];
  const float* mskA = (const float*)d_in[10];
  const float* mskB = (const float*)d_in[11];
  const float* temb = (const float*)d_in[12];
  const float* semb = (const float*)d_in[13];
  const float* conv_w = (const float*)d_in[14];
  const float* conv_b = (const float*)d_in[15];
  const float* cbn_g = (const float*)d_in[16];
  const float* cbn_b = (const float*)d_in[17];
  const float* cbn_rm = (const float*)d_in[18];
  const float* cbn_rv = (const float*)d_in[19];
  const float* hp_w = (const float*)d_in[20];
  const float* hp_b = (const float*)d_in[21];
  const float* qp_w = (const float*)d_in[22];
  const float* qp_b = (const float*)d_in[23];
  const float* attn_in_w = (const float*)d_in[24];
  const float* attn_in_b = (const float*)d_in[25];
  const float* attn_out_w = (const float*)d_in[26];
  const float* attn_out_b = (const float*)d_in[27];
  const float* ln_g = (const float*)d_in[28];
  const float* ln_b = (const float*)d_in[29];
  const float* tw_w = (const float*)d_in[30];
  const float* tw_b = (const float*)d_in[31];
  const float* tbn_g = (const float*)d_in[32];
  const float* tbn_b = (const float*)d_in[33];
  const float* tbn_rm = (const float*)d_in[34];
  const float* tbn_rv = (const float*)d_in[35];
  const float* r1_w = (const float*)d_in[36];
  const float* r1_b = (const float*)d_in[37];
  const float* r1bn_g = (const float*)d_in[38];
  const float* r1bn_b = (const float*)d_in[39];
  const float* r1bn_rm = (const float*)d_in[40];
  const float* r1bn_rv = (const float*)d_in[41];
  const float* r2_w = (const float*)d_in[42];
  const float* r2_b = (const float*)d_in[43];
  const float* r2bn_g = (const float*)d_in[44];
  const float* r2bn_b = (const float*)d_in[45];
  const float* r2bn_rm = (const float*)d_in[46];
  const float* r2bn_rv = (const float*)d_in[47];
  const float* mu_w = (const float*)d_in[48];
  const float* mu_b = (const float*)d_in[49];
  const float* lv_w = (const float*)d_in[50];
  const float* lv_b = (const float*)d_in[51];
  const float* wl_w = (const float*)d_in[52];
  const float* wl_b = (const float*)d_in[53];

  char* ws = (char*)d_ws;
  u16* w1f = (u16*)(ws + 0);             //  65536 B
  u16* w2f = (u16*)(ws + 65536);         //  16384 B
  float* woT = (float*)(ws + 81920);     //  16384 B (only 4096 floats used)
  float* Qg = (float*)(ws + 98304);      // 102400 B
  float* QHg = (float*)(ws + 200704);    // 102400 B
  float* twT = (float*)(ws + 303104);    // 133120 B
  float* r1T = (float*)(ws + 436224);    // 262144 B
  float* r2T = (float*)(ws + 698368);    // 262144 B
  float* ATT = (float*)(ws + 960512);    // 8388608 B

  prep_kernel<<<256, 256, 0, stream>>>(hp_w, conv_w, attn_in_w, attn_out_w,
                                       tw_w, r1_w, r2_w,
                                       w1f, w2f, woT, twT, r1T, r2T);
  team_kernel<<<400, 64, 0, stream>>>(temb, qp_w, qp_b, attn_in_w, attn_in_b, Qg, QHg);
  attn_kernel<<<2048, 256, 0, stream>>>(idA, idB, hnA, hnB, oppA, oppB, mskA, mskB,
                                        temb, conv_b, cbn_g, cbn_b, cbn_rm, cbn_rv,
                                        hp_b, attn_in_b, attn_out_b, ln_g, ln_b,
                                        w1f, w2f, woT, Qg, QHg, ATT);
  head_kernel<<<512, 256, 0, stream>>>(idA, idB, seedA, seedB, eloA, eloB, temb, semb,
                                       twT, tw_b, tbn_g, tbn_b, tbn_rm, tbn_rv,
                                       r1T, r1_b, r1bn_g, r1bn_b, r1bn_rm, r1bn_rv,
                                       r2T, r2_b, r2bn_g, r2bn_b, r2bn_rm, r2bn_rv,
                                       mu_w, mu_b, lv_w, lv_b, wl_w, wl_b,
                                       ATT, (float*)d_out);
}

// Round 14
// 527.594 us; speedup vs baseline: 1.0368x; 1.0229x over previous
//
#include <hip/hip_runtime.h>
#include <hip/hip_bf16.h>
#include <stdint.h>

#define EPS 1e-5f

typedef __attribute__((ext_vector_type(8))) short short8;
typedef __attribute__((ext_vector_type(4))) float floatx4;
typedef __attribute__((ext_vector_type(4))) unsigned uintx4;
typedef unsigned short u16;

// bf16 converts via the official HIP scalar intrinsic (RNE — bit-identical
// to the old manual round-half-even): compiler lowers to HW v_cvt. ROCm 7.2
// has no __floats2bfloat162_rn (r13 compile fail), so pack pairs manually —
// still ~3x fewer ops than the old software rounding.
__device__ __forceinline__ u16 f2bf(float f) {
  __hip_bfloat16 h = __float2bfloat16(f);
  return *reinterpret_cast<u16*>(&h);
}
__device__ __forceinline__ float bf2f(u16 h) {
  return __builtin_bit_cast(float, (unsigned)h << 16);
}
__device__ __forceinline__ unsigned pack2bf(float a, float b) {
  return (unsigned)f2bf(a) | ((unsigned)f2bf(b) << 16);
}
__device__ __forceinline__ float silu_f(float x) { return x / (1.f + __expf(-x)); }
__device__ __forceinline__ float wave_sum(float x) {
  for (int off = 32; off > 0; off >>= 1) x += __shfl_xor(x, off);
  return x;
}

// LDS-only barrier: drains ds ops (lgkmcnt) but NOT global loads (vmcnt).
// All cross-wave deps in attn_kernel are through LDS; global loads are
// register-consumed (compiler inserts vmcnt waits at each use).
#define BARRIER()                                         \
  do {                                                    \
    asm volatile("s_waitcnt lgkmcnt(0)" ::: "memory");    \
    __builtin_amdgcn_s_barrier();                         \
  } while (0)

// ---------------------------------------------------------------------------
// prep: swizzle weights into MFMA fragment order.
// w1f layout (conv-fold): [tap 0..3][nt 0..3][ks 0..3][lane][8]; tap 0..2 =
// conv taps, tap 3 = hp. woT packed [k4][64][4] for coalesced dwordx4.
// ---------------------------------------------------------------------------
__global__ void prep_kernel(const float* __restrict__ hp_w, const float* __restrict__ conv_w,
                            const float* __restrict__ attn_in_w,
                            const float* __restrict__ attn_out_w,
                            const float* __restrict__ tw_w, const float* __restrict__ r1_w,
                            const float* __restrict__ r2_w,
                            u16* __restrict__ w1f, u16* __restrict__ w2f,
                            float* __restrict__ woT,
                            float* __restrict__ twT, float* __restrict__ r1T,
                            float* __restrict__ r2T) {
  int t = blockIdx.x * 256 + threadIdx.x;  // 0..65535
  if (t < 32768) {
    int j = t & 7, lane = (t >> 3) & 63, ks = (t >> 9) & 3, nt = (t >> 11) & 3, tp = t >> 13;
    int k = ks * 32 + ((lane >> 4) << 3) + j;
    int c = nt * 16 + (lane & 15);
    float v = (tp == 3) ? hp_w[c * 128 + k] : conv_w[c * 384 + k * 3 + tp];
    w1f[t] = f2bf(v);
  }
  if (t < 8192) {
    int j = t & 7, lane = (t >> 3) & 63, ks = (t >> 9) & 1, nt = t >> 10;
    int k = ks * 32 + ((lane >> 4) << 3) + j;
    int n = nt * 16 + (lane & 15);
    w2f[t] = f2bf(attn_in_w[(64 + n) * 64 + k]);
  }
  if (t < 1024) {  // woT[(k4*64+j)*4+i] = attn_out_w[j][k4*4+i]
    int j = t & 63, k4 = t >> 6;
#pragma unroll
    for (int i = 0; i < 4; ++i)
      woT[(k4 * 64 + j) * 4 + i] = attn_out_w[j * 64 + k4 * 4 + i];
  }
  if (t < 8320) {  // twT[k4 0..64][mid 0..127][4]; k=257..259 zero-padded
    int mid = t & 127, k4 = t >> 7;
#pragma unroll
    for (int i = 0; i < 4; ++i) {
      int k = k4 * 4 + i;
      twT[t * 4 + i] = (k < 257) ? tw_w[mid * 257 + k] : 0.f;
    }
  }
  if (t < 16384) {  // r1T/r2T[k4 0..63][o 0..255][4]
    int o = t & 255, k4 = t >> 8;
#pragma unroll
    for (int i = 0; i < 4; ++i) {
      r1T[t * 4 + i] = r1_w[o * 256 + k4 * 4 + i];
      r2T[t * 4 + i] = r2_w[o * 256 + k4 * 4 + i];
    }
  }
}

// ---------------------------------------------------------------------------
// team_kernel: per-team q = temb[t]@qp_w.T + qp_b ; qh = q@wq.T + bq
// ---------------------------------------------------------------------------
__global__ __launch_bounds__(64) void team_kernel(
    const float* __restrict__ temb, const float* __restrict__ qp_w,
    const float* __restrict__ qp_b, const float* __restrict__ attn_in_w,
    const float* __restrict__ attn_in_b,
    float* __restrict__ Qg, float* __restrict__ QHg) {
  __shared__ float e[96];
  __shared__ float qv[64];
  const int t = blockIdx.x;   // team id 0..399
  const int o = threadIdx.x;  // 0..63
  for (int i = o; i < 96; i += 64) e[i] = temb[t * 96 + i];
  __syncthreads();
  float acc = qp_b[o];
  for (int k = 0; k < 96; ++k) acc += e[k] * qp_w[o * 96 + k];
  qv[o] = acc;
  Qg[t * 64 + o] = acc;
  __syncthreads();
  float acc2 = attn_in_b[o];
  for (int k = 0; k < 64; ++k) acc2 += qv[k] * attn_in_w[o * 64 + k];
  QHg[t * 64 + o] = acc2;
}

// ---------------------------------------------------------------------------
// attn_kernel (r22 = r20 + HW bf16 converts, compile-fixed). r20 structure
// (best attn, 235us): index-load software pipeline, lgkm-only barriers
// (4/unit), r8 tail split. ONLY change: f2bf via __float2bfloat16 (HW
// v_cvt, RNE) instead of ~5 ALU ops of manual rounding — targets the pack
// blocks on the barrier critical path.
// Diagnostics: VALUBusy 44.5 -> ~41-43; absmax must stay 0.00390625
// exactly; all other counters flat.
// ---------------------------------------------------------------------------
__global__ __launch_bounds__(256, 2) void attn_kernel(
    const int* __restrict__ idA, const int* __restrict__ idB,
    const float* __restrict__ hnA, const float* __restrict__ hnB,
    const int* __restrict__ oppA, const int* __restrict__ oppB,
    const float* __restrict__ mskA, const float* __restrict__ mskB,
    const float* __restrict__ temb, const float* __restrict__ conv_b,
    const float* __restrict__ cbn_g, const float* __restrict__ cbn_b,
    const float* __restrict__ cbn_rm, const float* __restrict__ cbn_rv,
    const float* __restrict__ hp_b,
    const float* __restrict__ attn_in_b, const float* __restrict__ attn_out_b,
    const float* __restrict__ ln_g, const float* __restrict__ ln_b,
    const u16* __restrict__ w1f, const u16* __restrict__ w2f,
    const float* __restrict__ woT,
    const float* __restrict__ Qg, const float* __restrict__ QHg,
    float* __restrict__ ATT) {
  // unified arena, 38976 B:
  //   [0,      11424) xs  : u16 [42][136]
  //   [11424,  18336) kvb : u16 [48][72]  (tail aliases a_s/op here)
  //   [18336,  38976) KVP : f32 [40][129]
  __shared__ __align__(16) u16 arena[19488];
  __shared__ __align__(16) float qh_s[2 * 64];
  u16* xs = arena;
  u16* kvb = arena + 5712;
  float* KVP = (float*)(arena + 9168);
  float* a_s = (float*)(arena + 5712);           // [8][40]
  float* op = a_s + 8 * 40;                      // [2][64] PV outputs

  const int tid = threadIdx.x;
  const int lane = tid & 63;
  const int wv = tid >> 6;
  const int qd = lane >> 4;
  const int l16 = lane & 15;
  const int qw = wv >> 1;    // tail: which q this wave serves
  const int hw = wv & 1;     // tail: which head-pair / dim-half

  const int c_lane = wv * 16 + l16;
  const float sc_c = rsqrtf(cbn_rv[c_lane] + EPS) * cbn_g[c_lane];
  const float sh_c = cbn_b[c_lane] - cbn_rm[c_lane] * sc_c;
  const float hpb_c = hp_b[c_lane];
  const float cvb_c = conv_b[c_lane];
  const float lng = ln_g[lane], lnb = ln_b[lane];
  const float aob = attn_out_b[lane];
  const float kb0 = attn_in_b[64 + (wv * 2 + 0) * 16 + l16];
  const float kb1 = attn_in_b[64 + (wv * 2 + 1) * 16 + l16];

  if (tid < 136) {
    xs[tid] = 0;
    xs[41 * 136 + tid] = 0;
  }

  short8 w1r[4][4];  // [tap: 0..2 conv, 3 hp][ks]
#pragma unroll
  for (int tp = 0; tp < 4; ++tp)
#pragma unroll
    for (int ks = 0; ks < 4; ++ks)
      w1r[tp][ks] = *reinterpret_cast<const short8*>(
          w1f + (((tp * 4 + wv) * 4 + ks) * 64 + lane) * 8);
  short8 w2r[2][2];
#pragma unroll
  for (int ntl = 0; ntl < 2; ++ntl)
#pragma unroll
    for (int ks = 0; ks < 2; ++ks)
      w2r[ntl][ks] = *reinterpret_cast<const short8*>(
          w2f + (((wv * 2 + ntl) * 2 + ks) * 64 + lane) * 8);

  // ---- unit-0 x data (one-time dependent loads, drained pre-loop) ----
  unsigned xr[12];
  float mkr[3];
  {
    int np = blockIdx.x;
    int pb = np >> 1;
    const float* phn = (np & 1) ? hnB : hnA;
    const int* popp = (np & 1) ? oppB : oppA;
    const float* pmsk = (np & 1) ? mskB : mskA;
#pragma unroll
    for (int j = 0; j < 3; ++j) {
      int sidx = j * 256 + tid;
      int srow = sidx >> 4, scg = sidx & 15;
      if (srow < 40) {
        int mrow = pb * 40 + srow;
        mkr[j] = pmsk[mrow];
        const float* p = (scg < 4)
                             ? phn + (size_t)mrow * 32 + scg * 8
                             : temb + (size_t)popp[mrow] * 96 + (scg * 8 - 32);
        floatx4 f0 = *reinterpret_cast<const floatx4*>(p);
        floatx4 f1 = *reinterpret_cast<const floatx4*>(p + 4);
        xr[j * 4 + 0] = pack2bf(f0[0], f0[1]);
        xr[j * 4 + 1] = pack2bf(f0[2], f0[3]);
        xr[j * 4 + 2] = pack2bf(f1[0], f1[1]);
        xr[j * 4 + 3] = pack2bf(f1[2], f1[3]);
      } else {
        mkr[j] = 0.f;
        xr[j * 4 + 0] = xr[j * 4 + 1] = xr[j * 4 + 2] = xr[j * 4 + 3] = 0u;
      }
    }
  }

  // ---- unit-0 q/mask + pipelined indices for unit 1 ----
  float qreg = 0.f, qhreg = 0.f, m_l = 0.f;
  int idn = 0;       // team id for unit 1 (wv<2)
  int oppn[3];       // popp row values for unit 1 staging
  {
    int b0i = blockIdx.x >> 1, s0 = blockIdx.x & 1;
    if (lane < 40) m_l = (s0 ? mskB : mskA)[b0i * 40 + lane];
    if (wv < 2) {
      int id0 = wv ? idB[b0i] : idA[b0i];
      qreg = Qg[id0 * 64 + lane];
      qhreg = QHg[id0 * 64 + lane];
      idn = wv ? idB[b0i + 1024] : idA[b0i + 1024];
    }
    int np1 = blockIdx.x + 2048;
    int pb1 = np1 >> 1;
    const int* popp1 = (np1 & 1) ? oppB : oppA;
#pragma unroll
    for (int j = 0; j < 3; ++j) {
      int srow = (j * 256 + tid) >> 4;
      oppn[j] = (srow < 40) ? popp1[pb1 * 40 + srow] : 0;
    }
  }
  BARRIER();  // pad-zero visible (LDS); prologue loads wait at use

#pragma unroll 1
  for (int it = 0; it < 8; ++it) {
    int pair = blockIdx.x + it * 2048;
    int b = pair >> 1, s = pair & 1;

    // stage x rows 1..40 (rows 0/41 stay zero)
#pragma unroll
    for (int j = 0; j < 3; ++j) {
      int sidx = j * 256 + tid;
      int srow = sidx >> 4;
      if (srow < 40) {
        bool keep = mkr[j] != 0.f;
        uintx4 v;
        v[0] = keep ? xr[j * 4 + 0] : 0u;
        v[1] = keep ? xr[j * 4 + 1] : 0u;
        v[2] = keep ? xr[j * 4 + 2] : 0u;
        v[3] = keep ? xr[j * 4 + 3] : 0u;
        *reinterpret_cast<uintx4*>(xs + (srow + 1) * 136 + (sidx & 15) * 8) = v;
      }
    }
    BARRIER();  // barrier1: xs ready

    // ---- prefetch slot: ALL loads independent, indices resident ----
    float pf[3][8];
    float mknew[3];
    float m_n = 0.f, qn = 0.f, qhn = 0.f;
    int idn2 = 0;
    {
      int np = (it < 7) ? pair + 2048 : pair;
      int pb = np >> 1;
      const float* phn = (np & 1) ? hnB : hnA;
      const float* pmsk = (np & 1) ? mskB : mskA;
#pragma unroll
      for (int j = 0; j < 3; ++j) {
        int sidx = j * 256 + tid;
        int srow = sidx >> 4, scg = sidx & 15;
        if (srow < 40) {
          int mrow = pb * 40 + srow;
          mknew[j] = pmsk[mrow];
          const float* p = (scg < 4)
                               ? phn + (size_t)mrow * 32 + scg * 8
                               : temb + (size_t)oppn[j] * 96 + (scg * 8 - 32);
          *reinterpret_cast<floatx4*>(&pf[j][0]) = *reinterpret_cast<const floatx4*>(p);
          *reinterpret_cast<floatx4*>(&pf[j][4]) = *reinterpret_cast<const floatx4*>(p + 4);
        } else {
          mknew[j] = 0.f;
#pragma unroll
          for (int q = 0; q < 8; ++q) pf[j][q] = 0.f;
        }
      }
      if (lane < 40) m_n = pmsk[pb * 40 + lane];   // tail mask for i+1
      if (wv < 2) {                                 // q gathers, idn resident
        qn = Qg[idn * 64 + lane];
        qhn = QHg[idn * 64 + lane];
      }
      // index loads for unit i+2 (direct, no deps)
      int np2 = (it < 6) ? pair + 4096 : pair;
      int pb2 = np2 >> 1;
      const int* popp2 = (np2 & 1) ? oppB : oppA;
#pragma unroll
      for (int j = 0; j < 3; ++j) {
        int srow = (j * 256 + tid) >> 4;
        oppn[j] = (srow < 40) ? popp2[pb2 * 40 + srow] : 0;
      }
      if (wv < 2) idn2 = wv ? idB[pb2] : idA[pb2];
    }

    // ---- GEMM1' conv-fold ----
#pragma unroll 1
    for (int mt = 0; mt < 3; ++mt) {
      floatx4 ach = {0.f, 0.f, 0.f, 0.f};
      floatx4 acv = {0.f, 0.f, 0.f, 0.f};
#pragma unroll
      for (int ks = 0; ks < 4; ++ks) {
        const u16* base = xs + (mt * 16 + l16) * 136 + ks * 32 + (qd << 3);
        short8 af0 = *reinterpret_cast<const short8*>(base);
        short8 af1 = *reinterpret_cast<const short8*>(base + 136);
        short8 af2 = *reinterpret_cast<const short8*>(base + 272);
        acv = __builtin_amdgcn_mfma_f32_16x16x32_bf16(af0, w1r[0][ks], acv, 0, 0, 0);
        acv = __builtin_amdgcn_mfma_f32_16x16x32_bf16(af1, w1r[1][ks], acv, 0, 0, 0);
        acv = __builtin_amdgcn_mfma_f32_16x16x32_bf16(af2, w1r[2][ks], acv, 0, 0, 0);
        ach = __builtin_amdgcn_mfma_f32_16x16x32_bf16(af1, w1r[3][ks], ach, 0, 0, 0);
      }
#pragma unroll
      for (int r = 0; r < 4; ++r) {
        float kv = silu_f(silu_f(ach[r] + hpb_c) + (acv[r] + cvb_c) * sc_c + sh_c);
        kvb[(mt * 16 + qd * 4 + r) * 72 + c_lane] = f2bf(kv);
      }
    }
    if (wv < 2) qh_s[wv * 64 + lane] = qhreg;
    BARRIER();  // barrier2: kvb + qh_s ready; prefetch loads still in flight

    // repack prefetched x (compiler places vmcnt waits here, at first use)
#pragma unroll
    for (int j = 0; j < 3; ++j) {
      xr[j * 4 + 0] = pack2bf(pf[j][0], pf[j][1]);
      xr[j * 4 + 1] = pack2bf(pf[j][2], pf[j][3]);
      xr[j * 4 + 2] = pack2bf(pf[j][4], pf[j][5]);
      xr[j * 4 + 3] = pack2bf(pf[j][6], pf[j][7]);
      mkr[j] = mknew[j];
    }

    {
      floatx4 acc[3][2] = {};
#pragma unroll
      for (int mt = 0; mt < 3; ++mt) {
        short8 af[2];
#pragma unroll
        for (int ks = 0; ks < 2; ++ks)
          af[ks] = *reinterpret_cast<const short8*>(
              kvb + (mt * 16 + l16) * 72 + ks * 32 + (qd << 3));
#pragma unroll
        for (int ntl = 0; ntl < 2; ++ntl)
#pragma unroll
          for (int ks = 0; ks < 2; ++ks)
            acc[mt][ntl] = __builtin_amdgcn_mfma_f32_16x16x32_bf16(
                af[ks], w2r[ntl][ks], acc[mt][ntl], 0, 0, 0);
      }
#pragma unroll
      for (int mt = 0; mt < 3; ++mt)
#pragma unroll
        for (int ntl = 0; ntl < 2; ++ntl)
#pragma unroll
          for (int r = 0; r < 4; ++r) {
            int row = mt * 16 + qd * 4 + r;
            if (row < 40)
              KVP[row * 129 + (wv * 2 + ntl) * 16 + l16] =
                  acc[mt][ntl][r] + (ntl ? kb1 : kb0);
          }
    }
    BARRIER();  // barrier3: KVP ready

    // ---- T2: scores — wave (qw,hw) computes heads hw*2, hw*2+1 for q=qw
    {
      float a2[2];
#pragma unroll
      for (int hh = 0; hh < 2; ++hh) {
        int h = hw * 2 + hh;
        float e = 0.f;
        if (lane < 40 && m_l > 0.f) {
          float s0 = 0.f, s1 = 0.f;
#pragma unroll
          for (int d = 0; d < 16; d += 2) {
            s0 += qh_s[qw * 64 + h * 16 + d] * KVP[lane * 129 + h * 16 + d];
            s1 += qh_s[qw * 64 + h * 16 + d + 1] * KVP[lane * 129 + h * 16 + d + 1];
          }
          e = __expf((s0 + s1) * 0.25f);
        }
        float sm = wave_sum(e);
        a2[hh] = e / sm;
      }
      if (lane < 40) {
        a_s[(qw * 4 + hw * 2 + 0) * 40 + lane] = a2[0];
        a_s[(qw * 4 + hw * 2 + 1) * 40 + lane] = a2[1];
      }
    }

    // ---- T3 (no barrier): PV for OWN heads' dims — d = hw*32+(lane&31),
    // l-half by lane>>5, combined via shfl_xor(32). Reads only a_s rows
    // this wave wrote (in-wave LDS ordering, compiler lgkmcnt).
    {
      int d = hw * 32 + (lane & 31);
      int arow = qw * 4 + (d >> 4);
      int l0 = (lane >> 5) * 20;
      float v0 = 0.f, v1 = 0.f;
#pragma unroll
      for (int li = 0; li < 20; li += 2) {
        int l = l0 + li;
        v0 += a_s[arow * 40 + l] * KVP[l * 129 + 64 + d];
        v1 += a_s[arow * 40 + l + 1] * KVP[(l + 1) * 129 + 64 + d];
      }
      float v = v0 + v1;
      v += __shfl_xor(v, 32);
      if (lane < 32) op[qw * 64 + d] = v;
    }
    BARRIER();  // barrier4: op ready for out-proj

    // ---- T4+T5: full out-proj + LN (waves 0,1); waves 2,3 run ahead ----
    if (wv < 2) {
      int qi = wv;
      float acc0 = aob + qreg, acc1 = 0.f;
      const floatx4* wo4 = reinterpret_cast<const floatx4*>(woT);
#pragma unroll 8
      for (int k4 = 0; k4 < 16; ++k4) {
        floatx4 w4 = wo4[k4 * 64 + lane];
        floatx4 x4 = *reinterpret_cast<const floatx4*>(&op[qi * 64 + k4 * 4]);
        acc0 += x4[0] * w4[0] + x4[2] * w4[2];
        acc1 += x4[1] * w4[1] + x4[3] * w4[3];
      }
      float r = acc0 + acc1;
      float mean = wave_sum(r) * (1.f / 64.f);
      float dv = r - mean;
      float var = wave_sum(dv * dv) * (1.f / 64.f);
      float outv = dv * rsqrtf(var + EPS) * lng + lnb;
      ATT[((qi * 2 + s) * 8192 + b) * 64 + lane] = outv;
    }

    // rotate pipelined state (registers only, no loads)
    qreg = qn;
    qhreg = qhn;
    m_l = m_n;
    idn = idn2;
  }
}

// ---------------------------------------------------------------------------
// head_kernel (r13 — unchanged control): 16 rows/block, aliased LDS arena.
// ---------------------------------------------------------------------------
__global__ __launch_bounds__(256) void head_kernel(
    const int* __restrict__ idA, const int* __restrict__ idB,
    const int* __restrict__ seedA, const int* __restrict__ seedB,
    const float* __restrict__ eloA, const float* __restrict__ eloB,
    const float* __restrict__ temb, const float* __restrict__ semb,
    const float* __restrict__ twT, const float* __restrict__ tw_b,
    const float* __restrict__ tbn_g, const float* __restrict__ tbn_b,
    const float* __restrict__ tbn_rm, const float* __restrict__ tbn_rv,
    const float* __restrict__ r1T, const float* __restrict__ r1_b,
    const float* __restrict__ r1bn_g, const float* __restrict__ r1bn_b,
    const float* __restrict__ r1bn_rm, const float* __restrict__ r1bn_rv,
    const float* __restrict__ r2T, const float* __restrict__ r2_b,
    const float* __restrict__ r2bn_g, const float* __restrict__ r2bn_b,
    const float* __restrict__ r2bn_rm, const float* __restrict__ r2bn_rv,
    const float* __restrict__ mu_w, const float* __restrict__ mu_b,
    const float* __restrict__ lv_w, const float* __restrict__ lv_b,
    const float* __restrict__ wl_w, const float* __restrict__ wl_b,
    const float* __restrict__ ATT, float* __restrict__ out) {
  __shared__ __align__(16) float smem[12416];  // 49664 B
  float* tv = smem;          // [2][16][260] (load + tower)
  float* rr = smem + 8320;   // [2][16][128]
  float* xv = smem;          // [16][256]    (after tower)
  float* xw = smem + 4096;   // [16][256]
  const int tid = threadIdx.x;
  const int b0 = blockIdx.x * 16;

  for (int idx = tid; idx < 2 * 16 * 260; idx += 256) {
    int k = idx % 260;
    int bi = (idx / 260) & 15;
    int team = idx / (260 * 16);
    int b = b0 + bi;
    float v;
    if (k < 96) v = temb[(team ? idB[b] : idA[b]) * 96 + k];
    else if (k < 128) v = semb[(team ? seedB[b] : seedA[b]) * 32 + (k - 96)];
    else if (k == 128) v = ((team ? eloB[b] : eloA[b]) - 1500.f) * (1.f / 400.f);
    else if (k < 193) v = ATT[((team * 2 + team) * 8192 + b) * 64 + (k - 129)];
    else if (k < 257) v = ATT[((team * 2 + (1 - team)) * 8192 + b) * 64 + (k - 193)];
    else v = 0.f;
    tv[(team * 16 + bi) * 260 + k] = v;
  }
  __syncthreads();

  {  // tower: 256 threads = 2 teams x 128 mids, 16 rows each
    int team = tid >> 7, mid = tid & 127;
    const floatx4* twv = reinterpret_cast<const floatx4*>(twT);
    float acc[16];
    float b_ = tw_b[mid];
#pragma unroll
    for (int bi = 0; bi < 16; ++bi) acc[bi] = b_;
#pragma unroll 2
    for (int k4 = 0; k4 < 65; ++k4) {
      floatx4 w4 = twv[k4 * 128 + mid];
#pragma unroll
      for (int bi = 0; bi < 16; ++bi) {
        floatx4 x4 = *reinterpret_cast<const floatx4*>(&tv[(team * 16 + bi) * 260 + k4 * 4]);
        acc[bi] += x4[0] * w4[0] + x4[1] * w4[1] + x4[2] * w4[2] + x4[3] * w4[3];
      }
    }
    float sc = rsqrtf(tbn_rv[mid] + EPS) * tbn_g[mid];
    float sh = tbn_b[mid] - tbn_rm[mid] * sc;
#pragma unroll
    for (int bi = 0; bi < 16; ++bi)
      rr[(team * 16 + bi) * 128 + mid] = silu_f(acc[bi] * sc + sh);
  }
  __syncthreads();
  {  // merge: xv overwrites tv region (all tv reads done before the barrier)
    int o = tid;
#pragma unroll
    for (int bi = 0; bi < 16; ++bi)
      xv[bi * 256 + o] = (o < 128)
                             ? (rr[bi * 128 + o] - rr[(16 + bi) * 128 + o])
                             : (rr[bi * 128 + o - 128] * rr[(16 + bi) * 128 + o - 128]);
  }
  __syncthreads();
  {  // r1: reads xv, writes xw
    int o = tid;
    const floatx4* r1v = reinterpret_cast<const floatx4*>(r1T);
    float acc[16];
    float b_ = r1_b[o];
#pragma unroll
    for (int bi = 0; bi < 16; ++bi) acc[bi] = b_;
#pragma unroll 2
    for (int k4 = 0; k4 < 64; ++k4) {
      floatx4 w4 = r1v[k4 * 256 + o];
#pragma unroll
      for (int bi = 0; bi < 16; ++bi) {
        floatx4 x4 = *reinterpret_cast<const floatx4*>(&xv[bi * 256 + k4 * 4]);
        acc[bi] += x4[0] * w4[0] + x4[1] * w4[1] + x4[2] * w4[2] + x4[3] * w4[3];
      }
    }
    float sc = rsqrtf(r1bn_rv[o] + EPS) * r1bn_g[o];
    float sh = r1bn_b[o] - r1bn_rm[o] * sc;
#pragma unroll
    for (int bi = 0; bi < 16; ++bi)
      xw[bi * 256 + o] = silu_f(acc[bi] * sc + sh) + xv[bi * 256 + o];
  }
  __syncthreads();
  {  // r2: reads xw, writes xv
    int o = tid;
    const floatx4* r2v = reinterpret_cast<const floatx4*>(r2T);
    float acc[16];
    float b_ = r2_b[o];
#pragma unroll
    for (int bi = 0; bi < 16; ++bi) acc[bi] = b_;
#pragma unroll 2
    for (int k4 = 0; k4 < 64; ++k4) {
      floatx4 w4 = r2v[k4 * 256 + o];
#pragma unroll
      for (int bi = 0; bi < 16; ++bi) {
        floatx4 x4 = *reinterpret_cast<const floatx4*>(&xw[bi * 256 + k4 * 4]);
        acc[bi] += x4[0] * w4[0] + x4[1] * w4[1] + x4[2] * w4[2] + x4[3] * w4[3];
      }
    }
    float sc = rsqrtf(r2bn_rv[o] + EPS) * r2bn_g[o];
    float sh = r2bn_b[o] - r2bn_rm[o] * sc;
#pragma unroll
    for (int bi = 0; bi < 16; ++bi)
      xv[bi * 256 + o] = silu_f(acc[bi] * sc + sh) + xw[bi * 256 + o];
  }
  __syncthreads();
  {  // heads: 256 threads = 16 rows x 16 outputs (mu 0..7, lv 0..7)
    int bi = tid >> 4, j = tid & 15;
    const float* wrow = (j < 8) ? (mu_w + j * 256) : (lv_w + (j - 8) * 256);
    const floatx4* wrow4 = reinterpret_cast<const floatx4*>(wrow);
    float acc = (j < 8) ? mu_b[j] : lv_b[j - 8];
#pragma unroll 4
    for (int k4 = 0; k4 < 64; ++k4) {
      floatx4 x4 = *reinterpret_cast<const floatx4*>(&xv[bi * 256 + k4 * 4]);
      floatx4 w4 = wrow4[k4];
      acc += x4[0] * w4[0] + x4[1] * w4[1] + x4[2] * w4[2] + x4[3] * w4[3];
    }
    int b = b0 + bi;
    if (j < 8) out[b * 8 + j] = acc;
    else out[65536 + b * 8 + (j - 8)] = acc;
    // win logit: 16 threads, one row each
    if (tid < 16) {
      const floatx4* wl4 = reinterpret_cast<const floatx4*>(wl_w);
      float acc2 = wl_b[0];
#pragma unroll 4
      for (int k4 = 0; k4 < 64; ++k4) {
        floatx4 x4 = *reinterpret_cast<const floatx4*>(&xv[tid * 256 + k4 * 4]);
        floatx4 w4 = wl4[k4];
        acc2 += x4[0] * w4[0] + x4[1] * w4[1] + x4[2] * w4[2] + x4[3] * w4[3];
      }
      out[131072 + b0 + tid] = acc2;
    }
  }
}

extern "C" void kernel_launch(void* const* d_in, const int* in_sizes, int n_in,
                              void* d_out, int out_size, void* d_ws, size_t ws_size,
                              hipStream_t stream) {
  const int* idA = (const int*)d_in[0];
  const int* idB = (const int*)d_in[1];
  const int* seedA = (const int*)d_in[2];
  const int* seedB = (const int*)d_in[3];
  const float* eloA = (const float*)d_in[4];
  const float* eloB = (const float*)d_in[5];
  const float* hnA = (const float*)d_in[6];
  const float* hnB = (const float*)d_in[7];
  const int* oppA = (const int*)d_in[8];
  const int* oppB = (const int*)d_in[9];
  const float* mskA = (const float*)d_in[10];
  const float* mskB = (const float*)d_in[11];
  const float* temb = (const float*)d_in[12];
  const float* semb = (const float*)d_in[13];
  const float* conv_w = (const float*)d_in[14];
  const float* conv_b = (const float*)d_in[15];
  const float* cbn_g = (const float*)d_in[16];
  const float* cbn_b = (const float*)d_in[17];
  const float* cbn_rm = (const float*)d_in[18];
  const float* cbn_rv = (const float*)d_in[19];
  const float* hp_w = (const float*)d_in[20];
  const float* hp_b = (const float*)d_in[21];
  const float* qp_w = (const float*)d_in[22];
  const float* qp_b = (const float*)d_in[23];
  const float* attn_in_w = (const float*)d_in[24];
  const float* attn_in_b = (const float*)d_in[25];
  const float* attn_out_w = (const float*)d_in[26];
  const float* attn_out_b = (const float*)d_in[27];
  const float* ln_g = (const float*)d_in[28];
  const float* ln_b = (const float*)d_in[29];
  const float* tw_w = (const float*)d_in[30];
  const float* tw_b = (const float*)d_in[31];
  const float* tbn_g = (const float*)d_in[32];
  const float* tbn_b = (const float*)d_in[33];
  const float* tbn_rm = (const float*)d_in[34];
  const float* tbn_rv = (const float*)d_in[35];
  const float* r1_w = (const float*)d_in[36];
  const float* r1_b = (const float*)d_in[37];
  const float* r1bn_g = (const float*)d_in[38];
  const float* r1bn_b = (const float*)d_in[39];
  const float* r1bn_rm = (const float*)d_in[40];
  const float* r1bn_rv = (const float*)d_in[41];
  const float* r2_w = (const float*)d_in[42];
  const float* r2_b = (const float*)d_in[43];
  const float* r2bn_g = (const float*)d_in[44];
  const float* r2bn_b = (const float*)d_in[45];
  const float* r2bn_rm = (const float*)d_in[46];
  const float* r2bn_rv = (const float*)d_in[47];
  const float* mu_w = (const float*)d_in[48];
  const float* mu_b = (const float*)d_in[49];
  const float* lv_w = (const float*)d_in[50];
  const float* lv_b = (const float*)d_in[51];
  const float* wl_w = (const float*)d_in[52];
  const float* wl_b = (const float*)d_in[53];

  char* ws = (char*)d_ws;
  u16* w1f = (u16*)(ws + 0);             //  65536 B
  u16* w2f = (u16*)(ws + 65536);         //  16384 B
  float* woT = (float*)(ws + 81920);     //  16384 B (only 4096 floats used)
  float* Qg = (float*)(ws + 98304);      // 102400 B
  float* QHg = (float*)(ws + 200704);    // 102400 B
  float* twT = (float*)(ws + 303104);    // 133120 B
  float* r1T = (float*)(ws + 436224);    // 262144 B
  float* r2T = (float*)(ws + 698368);    // 262144 B
  float* ATT = (float*)(ws + 960512);    // 8388608 B

  prep_kernel<<<256, 256, 0, stream>>>(hp_w, conv_w, attn_in_w, attn_out_w,
                                       tw_w, r1_w, r2_w,
                                       w1f, w2f, woT, twT, r1T, r2T);
  team_kernel<<<400, 64, 0, stream>>>(temb, qp_w, qp_b, attn_in_w, attn_in_b, Qg, QHg);
  attn_kernel<<<2048, 256, 0, stream>>>(idA, idB, hnA, hnB, oppA, oppB, mskA, mskB,
                                        temb, conv_b, cbn_g, cbn_b, cbn_rm, cbn_rv,
                                        hp_b, attn_in_b, attn_out_b, ln_g, ln_b,
                                        w1f, w2f, woT, Qg, QHg, ATT);
  head_kernel<<<512, 256, 0, stream>>>(idA, idB, seedA, seedB, eloA, eloB, temb, semb,
                                       twT, tw_b, tbn_g, tbn_b, tbn_rm, tbn_rv,
                                       r1T, r1_b, r1bn_g, r1bn_b, r1bn_rm, r1bn_rv,
                                       r2T, r2_b, r2bn_g, r2bn_b, r2bn_rm, r2bn_rv,
                                       mu_w, mu_b, lv_w, lv_b, wl_w, wl_b,
                                       ATT, (float*)d_out);
}